// Round 2
// baseline (23600.778 us; speedup 1.0000x reference)
//
#include <hip/hip_runtime.h>

#define NB 8
#define NPTS 16384
#define S 1024
#define KNEI 32
#define MROWS (NB*S*KNEI)   // 262144

// FPS multi-block geometry
#define BPB 8                  // blocks per batch (one per XCD slot)
#define PPB (NPTS/BPB)         // 2048 points per block
#define PPT (PPB/1024)         // 2 points per thread

// Value-only max combine via DPP (VALU pipe): pull value from another lane
// per CTRL, identity -1.0f for invalid lanes (all dists >= 0).
#define DPP_MAXF(CTRL, v) do {                                                \
    int _o = __builtin_amdgcn_update_dpp((int)0xBF800000, __float_as_int(v),  \
                                         (CTRL), 0xF, 0xF, false);            \
    float _f = __int_as_float(_o);                                            \
    (v) = fmaxf((v), _f);                                                     \
  } while (0)

// u64 key max combine via DPP (two 32-bit halves, identity 0: any real key
// has tag>=1 in bits 46+ so identity always loses).
#define DPP_MAXK(CTRL, k) do {                                                \
    unsigned _lo = (unsigned)(k), _hi = (unsigned)((k) >> 32);                \
    int _olo = __builtin_amdgcn_update_dpp(0, (int)_lo, (CTRL), 0xF, 0xF, false); \
    int _ohi = __builtin_amdgcn_update_dpp(0, (int)_hi, (CTRL), 0xF, 0xF, false); \
    unsigned long long _ok = (((unsigned long long)(unsigned)_ohi) << 32)     \
                           | (unsigned)_olo;                                  \
    if (_ok > (k)) (k) = _ok;                                                 \
  } while (0)

#define DPP_ROW_SHR1   0x111
#define DPP_ROW_SHR2   0x112
#define DPP_ROW_SHR4   0x114
#define DPP_ROW_SHR8   0x118
#define DPP_ROW_BCAST15 0x142
#define DPP_ROW_BCAST31 0x143

// ---------------------------------------------------------------------------
// FPS r11: r10 was still VALU-issue-bound on 8 CUs (VALUBusy = 78% of the
// 8/256-CU ceiling); the single-block structure floors at ~1.3 ms. Split each
// batch across BPB=8 blocks (2 pts/thread) and sync per step with device-scope
// 64-bit key slots:
//   key = (s+1)<<46 | float_bits(maxdist)<<14 | (16383 - idx)
// Tag embedded in the key => a single agent-scope release store publishes,
// a single acquire load consumes; no separate flag or fence. Parity
// ping-pong (global + LDS slots) makes overwrite safe at skew<=1 (2-phase
// barrier argument). blockIdx = k*8 + b keeps a batch's blocks on one XCD
// (perf heuristic only). 64 blocks are always co-resident (<=2048 thr/CU,
// tiny LDS) so the spin cannot deadlock. Slots live in d_out[0:128] (ull),
// zeroed before fps, overwritten later by maxpool.
// Exactness: distance math unchanged (no contraction, ((dx^2+dy^2)+dz^2)),
// f32 max is bit-exact under any order, smallest-index tie-break via the
// complemented index field (numpy argmax first-occurrence semantics).
// ---------------------------------------------------------------------------
__global__ __launch_bounds__(1024) void fps_kernel(const float* __restrict__ pos,
                                                   float* __restrict__ centers,
                                                   unsigned long long* __restrict__ gslots){
#pragma clang fp contract(off)
  __shared__ unsigned long long lslot[2][16];
  const int i  = blockIdx.x;
  const int b  = i & 7;                 // batch  (== XCD id heuristic)
  const int kb = i >> 3;                // block-within-batch 0..7
  const int t  = threadIdx.x;
  const int wid = t >> 6, lane = t & 63;
  const float* pb = pos + (size_t)b * NPTS * 3;
  const int p0 = kb*PPB + t*PPT;        // this thread's first point (global idx)

  float px[PPT], py[PPT], pz[PPT], dist[PPT];
  {
    const float2* src = (const float2*)(pb + (size_t)p0*3);  // 8B-aligned (p0 even)
    float2 a = src[0], c = src[1], e = src[2];
    px[0]=a.x; py[0]=a.y; pz[0]=c.x;
    px[1]=c.y; py[1]=e.x; pz[1]=e.y;
  }
#pragma unroll
  for (int j = 0; j < PPT; ++j){
    asm volatile("" : "+v"(px[j]), "+v"(py[j]), "+v"(pz[j]));  // no remat
    dist[j] = 1e10f;
  }
  float cx = pb[0], cy = pb[1], cz = pb[2];    // far=0 initial centroid

  for (int s = 0; s < S; ++s){
    if (kb == 0 && t == 0){
      float* cd = centers + (size_t)(b*S + s)*3;
      cd[0] = cx; cd[1] = cy; cd[2] = cz;
    }
    float bv = -1.0f;
#pragma unroll
    for (int j = 0; j < PPT; ++j){
      float dx = px[j]-cx, dy = py[j]-cy, dz = pz[j]-cz;
      float t1 = dx*dx, t2 = dy*dy, t3 = dz*dz;
      float d = (t1 + t2) + t3;
      float old = dist[j];
      float nd = old < d ? old : d;            // jnp.minimum
      dist[j] = nd;
      bv = fmaxf(bv, nd);
    }
    // wave-level value max (DPP)
    DPP_MAXF(DPP_ROW_SHR1,   bv);
    DPP_MAXF(DPP_ROW_SHR2,   bv);
    DPP_MAXF(DPP_ROW_SHR4,   bv);
    DPP_MAXF(DPP_ROW_SHR8,   bv);
    DPP_MAXF(DPP_ROW_BCAST15, bv);
    DPP_MAXF(DPP_ROW_BCAST31, bv);   // lane 63 = wave max
    float bm = __int_as_float(
        __builtin_amdgcn_readlane(__float_as_int(bv), 63));
    // locate smallest local j with dist[j]==bm (bit-copy => exact equality)
    int bj = PPT;
#pragma unroll
    for (int j = PPT-1; j >= 0; --j){
      if (dist[j] == bm) bj = j;
    }
    unsigned long long mk = __ballot(bj < PPT);   // nonzero: max is in-wave
    int l0 = (int)__builtin_ctzll(mk);            // lowest lane = smallest idx
    const int par = s & 1;
    const unsigned long long tag = (unsigned long long)(s + 1);
    if (lane == l0){
      unsigned long long key = (tag << 46)
          | ((unsigned long long)__float_as_uint(bm) << 14)
          | (unsigned long long)(16383 - (p0 + bj));
      lslot[par][wid] = key;
    }
    __syncthreads();
    if (wid == 0){
      // cross-wave u64 reduce (16 slots), lane 15 = block winner
      unsigned long long k2 = lslot[par][lane & 15];
      DPP_MAXK(DPP_ROW_SHR1, k2);
      DPP_MAXK(DPP_ROW_SHR2, k2);
      DPP_MAXK(DPP_ROW_SHR4, k2);
      DPP_MAXK(DPP_ROW_SHR8, k2);
      unsigned klo = (unsigned)__builtin_amdgcn_readlane((int)(unsigned)k2, 15);
      unsigned khi = (unsigned)__builtin_amdgcn_readlane((int)(unsigned)(k2 >> 32), 15);
      if (lane == 0){
        unsigned long long bk = (((unsigned long long)khi) << 32) | klo;
        __hip_atomic_store(&gslots[par*64 + b*8 + kb], bk,
                           __ATOMIC_RELEASE, __HIP_MEMORY_SCOPE_AGENT);
      }
    }
    // all waves: spin on this batch's 8 slots (tag check == s+1)
    unsigned long long kk;
    const unsigned long long* sl = &gslots[par*64 + b*8];
    for (;;){
      kk = __hip_atomic_load((unsigned long long*)&sl[lane & 7],
                             __ATOMIC_ACQUIRE, __HIP_MEMORY_SCOPE_AGENT);
      if (__all((int)((kk >> 46) == tag))) break;
    }
    // u64 max over lanes 0..7 of each row -> lane 7 holds batch winner
    DPP_MAXK(DPP_ROW_SHR1, kk);
    DPP_MAXK(DPP_ROW_SHR2, kk);
    DPP_MAXK(DPP_ROW_SHR4, kk);
    unsigned wlo = (unsigned)__builtin_amdgcn_readlane((int)(unsigned)kk, 7);
    unsigned whi = (unsigned)__builtin_amdgcn_readlane((int)(unsigned)(kk >> 32), 7);
    unsigned long long kmax = (((unsigned long long)whi) << 32) | wlo;
    int ufi = 16383 - (int)(kmax & 0x3FFFull);
    cx = pb[ufi*3+0];                  // uniform, L2-hot
    cy = pb[ufi*3+1];
    cz = pb[ufi*3+2];
  }
}

// ---------------------------------------------------------------------------
// Ball query: one wave per center. Ordered compaction of the first 32
// in-radius indices (ascending index order == jnp.sort-then-truncate).
// ---------------------------------------------------------------------------
__global__ __launch_bounds__(256) void ballq_kernel(const float* __restrict__ pos,
                                                    const float* __restrict__ centers,
                                                    int* __restrict__ idx){
#pragma clang fp contract(off)
  const float R2 = (float)(0.2*0.2);   // match Python double 0.2*0.2 -> f32
  int wid  = blockIdx.x*4 + (threadIdx.x >> 6);
  int lane = threadIdx.x & 63;
  int b = wid >> 10;                   // wid / S
  const float* pb = pos + (size_t)b * NPTS * 3;
  float cx = centers[wid*3+0], cy = centers[wid*3+1], cz = centers[wid*3+2];
  int* out = idx + wid*KNEI;
  int count = 0; int first = -1;
  for (int base = 0; base < NPTS; base += 64){
    int p = base + lane;
    float dx = pb[p*3+0]-cx, dy = pb[p*3+1]-cy, dz = pb[p*3+2]-cz;
    float t1 = dx*dx, t2 = dy*dy, t3 = dz*dz;
    float d = (t1 + t2) + t3;
    bool inr = d <= R2;
    unsigned long long mask = __ballot(inr);
    if (count == 0 && mask) first = base + __builtin_ctzll(mask);
    if (inr){
      int slot = count + __popcll(mask & ((1ull << lane) - 1ull));
      if (slot < KNEI) out[slot] = p;
    }
    count += __popcll(mask);
    if (count >= KNEI) break;
  }
  if (count < KNEI){
    for (int slot = count + lane; slot < KNEI; slot += 64) out[slot] = first;
  }
}

// ---------------------------------------------------------------------------
// GEMM1 sem: h1[m][0:64] = feat[b, idx[m], :] @ w(64x64) + bias.
// Block: 256 threads, 64-row tile. Also accumulates per-channel sum/sumsq.
// ---------------------------------------------------------------------------
__global__ __launch_bounds__(256) void gemm_sem1(const float* __restrict__ feat,
    const int* __restrict__ idx, const float* __restrict__ w,
    const float* __restrict__ bias, float* __restrict__ h1,
    float* __restrict__ stat){
  __shared__ float xs[64][68];
  __shared__ float wsh[64][64];
  const int tid = threadIdx.x;
  const int m0 = blockIdx.x * 64;
#pragma unroll
  for (int i = 0; i < 4; ++i){
    int q = tid + i*256;                 // 1024 quads of w (64x64)
    int r = q >> 4, c4 = q & 15;
    *(float4*)&wsh[r][c4*4] = *(const float4*)&w[r*64 + c4*4];
  }
#pragma unroll
  for (int i = 0; i < 4; ++i){
    int q = tid + i*256;                 // 1024 quads of x tile (64x64)
    int r = q >> 4, c4 = q & 15;
    int m = m0 + r;
    int nb = idx[m];
    int b = m >> 15;                     // m / (S*KNEI)
    const float* fr = feat + ((size_t)b*NPTS + nb)*64;
    *(float4*)&xs[r][c4*4] = *(const float4*)&fr[c4*4];
  }
  __syncthreads();
  const int g  = tid & 7;                // channel group: 8 channels
  const int rt = tid >> 3;               // 32 row-threads, 2 rows each
  const int r0 = rt * 2;
  float acc[2][8];
#pragma unroll
  for (int c = 0; c < 8; ++c){ float bb = bias[g*8+c]; acc[0][c] = bb; acc[1][c] = bb; }
  for (int k = 0; k < 64; ++k){
    float x0 = xs[r0][k], x1 = xs[r0+1][k];
    float4 wa = *(float4*)&wsh[k][g*8];
    float4 wb = *(float4*)&wsh[k][g*8+4];
    float wv[8] = {wa.x,wa.y,wa.z,wa.w,wb.x,wb.y,wb.z,wb.w};
#pragma unroll
    for (int c = 0; c < 8; ++c){ acc[0][c] += x0*wv[c]; acc[1][c] += x1*wv[c]; }
  }
#pragma unroll
  for (int r = 0; r < 2; ++r){
    float* dst = h1 + (size_t)(m0 + r0 + r)*64 + g*8;
    *(float4*)dst     = make_float4(acc[r][0],acc[r][1],acc[r][2],acc[r][3]);
    *(float4*)(dst+4) = make_float4(acc[r][4],acc[r][5],acc[r][6],acc[r][7]);
  }
  float ls[8], lq[8];
#pragma unroll
  for (int c = 0; c < 8; ++c){
    ls[c] = acc[0][c] + acc[1][c];
    lq[c] = acc[0][c]*acc[0][c] + acc[1][c]*acc[1][c];
  }
  __syncthreads();
  float* red  = &xs[0][0];
  float* redq = &wsh[0][0];
#pragma unroll
  for (int c = 0; c < 8; ++c){
    red[(g*8+c)*32 + rt]  = ls[c];
    redq[(g*8+c)*32 + rt] = lq[c];
  }
  __syncthreads();
  if (tid < 128){
    int c = tid & 63;
    const float* src = (tid < 64) ? red : redq;
    float a2 = 0.f;
    for (int i = 0; i < 32; ++i) a2 += src[c*32+i];
    atomicAdd(&stat[(tid < 64 ? 0 : 64) + c], a2);
  }
}

// ---------------------------------------------------------------------------
// GEMM2 (sem & geo layer 2): x = relu(a*hin+d) (folded BN1), out 128 ch.
// ---------------------------------------------------------------------------
__global__ __launch_bounds__(256) void gemm2_kernel(const float* __restrict__ hin,
    const float* __restrict__ abn, const float* __restrict__ dbn,
    const float* __restrict__ w, const float* __restrict__ bias,
    float* __restrict__ hout, float* __restrict__ stat){
  __shared__ float xs[64][68];
  __shared__ float wsh[64][128];
  const int tid = threadIdx.x;
  const int m0 = blockIdx.x * 64;
#pragma unroll
  for (int i = 0; i < 8; ++i){
    int q = tid + i*256;                 // 2048 quads of w (64x128)
    int r = q >> 5, c4 = q & 31;
    *(float4*)&wsh[r][c4*4] = *(const float4*)&w[r*128 + c4*4];
  }
#pragma unroll
  for (int i = 0; i < 4; ++i){
    int q = tid + i*256;
    int r = q >> 4, c4 = q & 15;
    float4 v  = *(const float4*)&hin[(size_t)(m0+r)*64 + c4*4];
    float4 av = *(const float4*)&abn[c4*4];
    float4 dv = *(const float4*)&dbn[c4*4];
    v.x = fmaxf(v.x*av.x + dv.x, 0.f);
    v.y = fmaxf(v.y*av.y + dv.y, 0.f);
    v.z = fmaxf(v.z*av.z + dv.z, 0.f);
    v.w = fmaxf(v.w*av.w + dv.w, 0.f);
    *(float4*)&xs[r][c4*4] = v;
  }
  __syncthreads();
  const int g  = tid & 15;               // 16 groups x 8 ch = 128
  const int rt = tid >> 4;               // 16 row-threads x 4 rows = 64
  const int r0 = rt * 4;
  float acc[4][8];
#pragma unroll
  for (int c = 0; c < 8; ++c){
    float bb = bias[g*8+c];
    acc[0][c]=bb; acc[1][c]=bb; acc[2][c]=bb; acc[3][c]=bb;
  }
  for (int k = 0; k < 64; ++k){
    float x0 = xs[r0][k], x1 = xs[r0+1][k], x2 = xs[r0+2][k], x3 = xs[r0+3][k];
    float4 wa = *(float4*)&wsh[k][g*8];
    float4 wb = *(float4*)&wsh[k][g*8+4];
    float wv[8] = {wa.x,wa.y,wa.z,wa.w,wb.x,wb.y,wb.z,wb.w};
#pragma unroll
    for (int c = 0; c < 8; ++c){
      acc[0][c] += x0*wv[c]; acc[1][c] += x1*wv[c];
      acc[2][c] += x2*wv[c]; acc[3][c] += x3*wv[c];
    }
  }
#pragma unroll
  for (int r = 0; r < 4; ++r){
    float* dst = hout + (size_t)(m0 + r0 + r)*128 + g*8;
    *(float4*)dst     = make_float4(acc[r][0],acc[r][1],acc[r][2],acc[r][3]);
    *(float4*)(dst+4) = make_float4(acc[r][4],acc[r][5],acc[r][6],acc[r][7]);
  }
  float ls[8], lq[8];
#pragma unroll
  for (int c = 0; c < 8; ++c){
    ls[c] = acc[0][c]+acc[1][c]+acc[2][c]+acc[3][c];
    lq[c] = acc[0][c]*acc[0][c]+acc[1][c]*acc[1][c]+acc[2][c]*acc[2][c]+acc[3][c]*acc[3][c];
  }
  __syncthreads();
  float* red = &xs[0][0];                // 2048 sums + 2048 sumsq (fits 64*68)
#pragma unroll
  for (int c = 0; c < 8; ++c){
    red[(g*8+c)*16 + rt]        = ls[c];
    red[2048 + (g*8+c)*16 + rt] = lq[c];
  }
  __syncthreads();
  {
    int c = tid & 127;
    int isq = tid >> 7;
    float a2 = 0.f;
    for (int i = 0; i < 16; ++i) a2 += red[isq*2048 + c*16 + i];
    atomicAdd(&stat[isq*128 + c], a2);
  }
}

// ---------------------------------------------------------------------------
// GEMM1 geo: x = [center(3) | grouped_pos(3)] (6 ch) @ w(6x64) + bias.
// ---------------------------------------------------------------------------
__global__ __launch_bounds__(256) void gemm_geo1(const float* __restrict__ pos,
    const float* __restrict__ centers, const int* __restrict__ idx,
    const float* __restrict__ w, const float* __restrict__ bias,
    float* __restrict__ hout, float* __restrict__ stat){
  __shared__ float xs[64][8];
  __shared__ float wsh[6][64];
  __shared__ float red[2048];
  __shared__ float redq[2048];
  const int tid = threadIdx.x;
  const int m0 = blockIdx.x * 64;
  for (int i = tid; i < 384; i += 256) wsh[i >> 6][i & 63] = w[i];
  if (tid < 64){
    int m = m0 + tid;
    int grp = m >> 5;                    // m / KNEI
    int b = m >> 15;
    int nb = idx[m];
    const float* cp = centers + (size_t)grp*3;
    const float* pp = pos + ((size_t)b*NPTS + nb)*3;
    xs[tid][0]=cp[0]; xs[tid][1]=cp[1]; xs[tid][2]=cp[2];
    xs[tid][3]=pp[0]; xs[tid][4]=pp[1]; xs[tid][5]=pp[2];
  }
  __syncthreads();
  const int g  = tid & 7;
  const int rt = tid >> 3;
  const int r0 = rt * 2;
  float acc[2][8];
#pragma unroll
  for (int c = 0; c < 8; ++c){ float bb = bias[g*8+c]; acc[0][c]=bb; acc[1][c]=bb; }
#pragma unroll
  for (int k = 0; k < 6; ++k){
    float x0 = xs[r0][k], x1 = xs[r0+1][k];
    float4 wa = *(float4*)&wsh[k][g*8];
    float4 wb = *(float4*)&wsh[k][g*8+4];
    float wv[8] = {wa.x,wa.y,wa.z,wa.w,wb.x,wb.y,wb.z,wb.w};
#pragma unroll
    for (int c = 0; c < 8; ++c){ acc[0][c] += x0*wv[c]; acc[1][c] += x1*wv[c]; }
  }
#pragma unroll
  for (int r = 0; r < 2; ++r){
    float* dst = hout + (size_t)(m0 + r0 + r)*64 + g*8;
    *(float4*)dst     = make_float4(acc[r][0],acc[r][1],acc[r][2],acc[r][3]);
    *(float4*)(dst+4) = make_float4(acc[r][4],acc[r][5],acc[r][6],acc[r][7]);
  }
  float ls[8], lq[8];
#pragma unroll
  for (int c = 0; c < 8; ++c){
    ls[c] = acc[0][c] + acc[1][c];
    lq[c] = acc[0][c]*acc[0][c] + acc[1][c]*acc[1][c];
  }
#pragma unroll
  for (int c = 0; c < 8; ++c){
    red[(g*8+c)*32 + rt]  = ls[c];
    redq[(g*8+c)*32 + rt] = lq[c];
  }
  __syncthreads();
  if (tid < 128){
    int c = tid & 63;
    const float* src = (tid < 64) ? red : redq;
    float a2 = 0.f;
    for (int i = 0; i < 32; ++i) a2 += src[c*32+i];
    atomicAdd(&stat[(tid < 64 ? 0 : 64) + c], a2);
  }
}

// ---------------------------------------------------------------------------
// BN finalize: fold stats into per-channel scale/shift a,d.
// ---------------------------------------------------------------------------
__global__ void bn_finalize(const float* __restrict__ stat,
                            const float* __restrict__ gam, const float* __restrict__ bet,
                            float* __restrict__ a, float* __restrict__ d, int C){
  int c = threadIdx.x;
  if (c >= C) return;
  const float invM = 1.0f / (float)MROWS;
  float mu  = stat[c] * invM;
  float ex2 = stat[C + c] * invM;
  float var = ex2 - mu*mu;
  float aa = gam[c] * rsqrtf(var + 1e-5f);
  a[c] = aa;
  d[c] = bet[c] - mu*aa;
}

// ---------------------------------------------------------------------------
// Max over K with folded BN2 + ReLU: out[grp][c] = relu(max_k (a*h+d)).
// ---------------------------------------------------------------------------
__global__ __launch_bounds__(256) void maxpool_kernel(const float* __restrict__ hin,
    const float* __restrict__ abn, const float* __restrict__ dbn,
    float* __restrict__ out){
  const int tid = threadIdx.x;
  const int grp = blockIdx.x*8 + (tid >> 5);
  const int c4 = tid & 31;
  const float* base = hin + (size_t)grp*KNEI*128 + c4*4;
  float4 a = *(const float4*)&abn[c4*4];
  float4 d = *(const float4*)&dbn[c4*4];
  float4 m = make_float4(-3.4e38f,-3.4e38f,-3.4e38f,-3.4e38f);
  for (int k = 0; k < KNEI; ++k){
    float4 v = *(const float4*)&base[(size_t)k*128];
    m.x = fmaxf(m.x, v.x*a.x + d.x);
    m.y = fmaxf(m.y, v.y*a.y + d.y);
    m.z = fmaxf(m.z, v.z*a.z + d.z);
    m.w = fmaxf(m.w, v.w*a.w + d.w);
  }
  m.x = fmaxf(m.x, 0.f); m.y = fmaxf(m.y, 0.f);
  m.z = fmaxf(m.z, 0.f); m.w = fmaxf(m.w, 0.f);
  *(float4*)&out[(size_t)grp*128 + c4*4] = m;
}

__global__ void zero_kernel(float* __restrict__ p, int n){
  int i = blockIdx.x*blockDim.x + threadIdx.x;
  if (i < n) p[i] = 0.f;
}

extern "C" void kernel_launch(void* const* d_in, const int* in_sizes, int n_in,
                              void* d_out, int out_size, void* d_ws, size_t ws_size,
                              hipStream_t stream){
  const float* pos   = (const float*)d_in[0];
  const float* feat  = (const float*)d_in[1];
  const float* w_s1  = (const float*)d_in[2];
  const float* b_s1  = (const float*)d_in[3];
  const float* g_s1  = (const float*)d_in[4];
  const float* be_s1 = (const float*)d_in[5];
  const float* w_s2  = (const float*)d_in[6];
  const float* b_s2  = (const float*)d_in[7];
  const float* g_s2  = (const float*)d_in[8];
  const float* be_s2 = (const float*)d_in[9];
  const float* w_g1  = (const float*)d_in[10];
  const float* b_g1  = (const float*)d_in[11];
  const float* g_g1  = (const float*)d_in[12];
  const float* be_g1 = (const float*)d_in[13];
  const float* w_g2  = (const float*)d_in[14];
  const float* b_g2  = (const float*)d_in[15];
  const float* g_g2  = (const float*)d_in[16];
  const float* be_g2 = (const float*)d_in[17];
  float* outp = (float*)d_out;
  float* wsf  = (float*)d_ws;

  // workspace layout (floats):
  float* centers = wsf;                         // 8192*3 = 24576
  int*   idxp    = (int*)(wsf + 24576);         // 262144
  float* stats   = wsf + 24576 + 262144;        // 768
  float* bnad    = stats + 768;                 // 768
  float* h1      = wsf + 288256;                // 262144*64
  float* h2      = h1 + (size_t)MROWS*64;       // 262144*128
  // total = 50,619,904 floats = ~193.1 MiB

  // fps sync slots: first 1 KiB of d_out (2 parities x 64 u64). d_out is
  // unused until maxpool (which fully overwrites it); zeroed here so stale
  // tags can never alias a live step tag on graph replay.
  unsigned long long* gslots = (unsigned long long*)d_out;

  float* st1 = stats;        // 64 sum + 64 sq
  float* st2 = stats + 128;  // 128 + 128
  float* st3 = stats + 384;  // 64 + 64
  float* st4 = stats + 512;  // 128 + 128
  float* a1 = bnad;        float* d1 = bnad + 64;
  float* a2 = bnad + 128;  float* d2 = bnad + 256;
  float* a3 = bnad + 384;  float* d3 = bnad + 448;
  float* a4 = bnad + 512;  float* d4 = bnad + 640;

  zero_kernel<<<3, 256, 0, stream>>>(stats, 768);
  zero_kernel<<<1, 256, 0, stream>>>((float*)d_out, 256);   // 128 ull slots
  fps_kernel<<<NB*BPB, 1024, 0, stream>>>(pos, centers, gslots);
  ballq_kernel<<<(NB*S)/4, 256, 0, stream>>>(pos, centers, idxp);

  // sem branch
  gemm_sem1<<<MROWS/64, 256, 0, stream>>>(feat, idxp, w_s1, b_s1, h1, st1);
  bn_finalize<<<1, 128, 0, stream>>>(st1, g_s1, be_s1, a1, d1, 64);
  gemm2_kernel<<<MROWS/64, 256, 0, stream>>>(h1, a1, d1, w_s2, b_s2, h2, st2);
  bn_finalize<<<1, 128, 0, stream>>>(st2, g_s2, be_s2, a2, d2, 128);
  maxpool_kernel<<<(NB*S)/8, 256, 0, stream>>>(h2, a2, d2, outp);

  // geo branch (reuses h1/h2)
  gemm_geo1<<<MROWS/64, 256, 0, stream>>>(pos, centers, idxp, w_g1, b_g1, h1, st3);
  bn_finalize<<<1, 128, 0, stream>>>(st3, g_g1, be_g1, a3, d3, 64);
  gemm2_kernel<<<MROWS/64, 256, 0, stream>>>(h1, a3, d3, w_g2, b_g2, h2, st4);
  bn_finalize<<<1, 128, 0, stream>>>(st4, g_g2, be_g2, a4, d4, 128);
  maxpool_kernel<<<(NB*S)/8, 256, 0, stream>>>(h2, a4, d4, outp + (size_t)NB*S*128);
}

// Round 3
// 2219.460 us; speedup vs baseline: 10.6336x; 10.6336x over previous
//
#include <hip/hip_runtime.h>

#define NB 8
#define NPTS 16384
#define S 1024
#define KNEI 32
#define MROWS (NB*S*KNEI)   // 262144

// Dynamic LDS for fps: x[16384] + 2*16 u64 key slots.
#define FPS_LDS_BYTES (NPTS*4 + 2*16*8)   // 65792 B

typedef float v2f __attribute__((ext_vector_type(2)));

// Value-only max combine via DPP, bound_ctrl=1 (invalid lanes read 0 --
// safe identity: all reduced values are >= 0).
#define DPP_MAXF0(CTRL, v) do {                                               \
    int _o = __builtin_amdgcn_update_dpp(0, __float_as_int(v),                \
                                         (CTRL), 0xF, 0xF, true);             \
    (v) = fmaxf((v), __int_as_float(_o));                                     \
  } while (0)

// u64 key max combine via DPP halves, bound_ctrl=1 (identity 0 always loses:
// every real key >= 1 because of the 16384-idx field).
#define DPP_MAXK0(CTRL, k) do {                                               \
    int _olo = __builtin_amdgcn_update_dpp(0, (int)(unsigned)(k),             \
                                           (CTRL), 0xF, 0xF, true);           \
    int _ohi = __builtin_amdgcn_update_dpp(0, (int)(unsigned)((k) >> 32),     \
                                           (CTRL), 0xF, 0xF, true);           \
    unsigned long long _ok = (((unsigned long long)(unsigned)_ohi) << 32)     \
                           | (unsigned)_olo;                                  \
    if (_ok > (k)) (k) = _ok;                                                 \
  } while (0)

#define DPP_ROW_SHR1   0x111
#define DPP_ROW_SHR2   0x112
#define DPP_ROW_SHR4   0x114
#define DPP_ROW_SHR8   0x118
#define DPP_ROW_BCAST15 0x142
#define DPP_ROW_BCAST31 0x143

// ---------------------------------------------------------------------------
// FPS r12: r11's cross-block global sync cost 22.8us/step (agent-scope
// coherence point is past L2 on gfx950) -- reverted to the r10 single-CU
// structure and cut wave-instructions instead (r10 measured ~396/wave/step):
//  * packed f32 (<2 x float> -> v_pk_add/mul_f32) for the distance loop
//  * fminf/fmaxf -> v_min_f32 / v_max3_f32 (exact for this no-NaN data)
//  * one barrier/step: per-wave u64 key (dist_bits<<15 | 16384-idx) -> LDS
//    -> 16-slot u64 DPP reduce (parity-double-buffered slots)
//  * bound_ctrl=1 DPP (identity 0; valid since dists >= 0)
//  * dx^2 pass runs on cx (fast LDS) before cy/cz (global) are needed,
//    hiding the uniform-load latency under issue work.
// Exact-match discipline: no fp contraction, ((dx^2+dy^2)+dz^2) order,
// first-occurrence argmax via complemented-index key field.
// ---------------------------------------------------------------------------
__global__ __launch_bounds__(1024) void fps_kernel(const float* __restrict__ pos,
                                                   float* __restrict__ centers){
#pragma clang fp contract(off)
  extern __shared__ float smem[];
  float* sx = smem;                                        // [NPTS]
  unsigned long long* lslot = (unsigned long long*)(smem + NPTS);  // [2][16]
  const int b = blockIdx.x;
  const int t = threadIdx.x;
  const int wid = t >> 6, lane = t & 63;
  const float* pb = pos + (size_t)b * NPTS * 3;
  const int p0 = t * 16;                 // this thread's first point index

  v2f px[8], py[8], pz[8], dist[8];
  {
    float c[48];
    const float4* src = (const float4*)(pb + (size_t)t*48);
#pragma unroll
    for (int q = 0; q < 12; ++q) *(float4*)&c[q*4] = src[q];
#pragma unroll
    for (int j = 0; j < 8; ++j){
      px[j] = (v2f){c[6*j+0], c[6*j+3]};
      py[j] = (v2f){c[6*j+1], c[6*j+4]};
      pz[j] = (v2f){c[6*j+2], c[6*j+5]};
    }
    // stage x plane into LDS (centroid-x broadcast reads)
#pragma unroll
    for (int g = 0; g < 4; ++g){
      *(float4*)&sx[p0 + g*4] =
          make_float4(c[12*g+0], c[12*g+3], c[12*g+6], c[12*g+9]);
    }
  }
#pragma unroll
  for (int j = 0; j < 8; ++j){
    asm volatile("" : "+v"(px[j]), "+v"(py[j]), "+v"(pz[j]));  // no remat
    dist[j] = (v2f){1e10f, 1e10f};
  }
  float cx = pb[0], cy = pb[1], cz = pb[2];    // far=0 initial centroid
  __syncthreads();

  for (int s = 0; s < S; ++s){
    if (t == 0){
      float* cd = centers + (size_t)(b*S + s)*3;
      cd[0] = cx; cd[1] = cy; cd[2] = cz;
    }
    // pass A: dx^2 only (cx is LDS-fast; cy/cz may still be in flight)
    v2f dxx[8];
    {
      v2f c2 = (v2f){cx, cx};
#pragma unroll
      for (int j = 0; j < 8; ++j){
        v2f dx = px[j] - c2;
        dxx[j] = dx * dx;
      }
    }
    // pass B: finish distance, min-update, running max
    float bv = 0.0f;
    {
      v2f cy2 = (v2f){cy, cy}, cz2 = (v2f){cz, cz};
#pragma unroll
      for (int j = 0; j < 8; ++j){
        v2f dy = py[j] - cy2;
        v2f dz = pz[j] - cz2;
        v2f t2 = dy * dy;
        v2f t3 = dz * dz;
        v2f d  = (dxx[j] + t2) + t3;     // ((dx^2+dy^2)+dz^2)
        v2f od = dist[j];
        v2f nd = (v2f){__builtin_fminf(od.x, d.x), __builtin_fminf(od.y, d.y)};
        dist[j] = nd;
        bv = fmaxf(fmaxf(bv, nd.x), nd.y);   // v_max3
      }
    }
    // wave-level value max (DPP)
    DPP_MAXF0(DPP_ROW_SHR1,   bv);
    DPP_MAXF0(DPP_ROW_SHR2,   bv);
    DPP_MAXF0(DPP_ROW_SHR4,   bv);
    DPP_MAXF0(DPP_ROW_SHR8,   bv);
    DPP_MAXF0(DPP_ROW_BCAST15, bv);
    DPP_MAXF0(DPP_ROW_BCAST31, bv);   // lane 63 = wave max
    float bm = __int_as_float(
        __builtin_amdgcn_readlane(__float_as_int(bv), 63));
    // smallest local j with dist[j]==bm (bit-copy => exact equality)
    int bj = 16;
#pragma unroll
    for (int j = 7; j >= 0; --j){
      if (dist[j].y == bm) bj = 2*j+1;
      if (dist[j].x == bm) bj = 2*j;
    }
    unsigned long long mk = __ballot(bj < 16);    // nonzero: bm is in-wave
    int l0 = (int)__builtin_ctzll(mk);            // lowest lane = smallest idx
    int wc = __builtin_amdgcn_readlane(p0 + bj, l0);
    const int par = s & 1;
    if (lane == 0){
      lslot[par*16 + wid] = ((unsigned long long)__float_as_uint(bm) << 15)
                          | (unsigned long long)(16384 - wc);
    }
    __syncthreads();
    // cross-wave u64 reduce: 16 slots on lanes 0-15 of each row
    unsigned long long kk = lslot[par*16 + (lane & 15)];
    DPP_MAXK0(DPP_ROW_SHR1, kk);
    DPP_MAXK0(DPP_ROW_SHR2, kk);
    DPP_MAXK0(DPP_ROW_SHR4, kk);
    DPP_MAXK0(DPP_ROW_SHR8, kk);
    unsigned klo = (unsigned)__builtin_amdgcn_readlane((int)(unsigned)kk, 15);
    unsigned khi = (unsigned)__builtin_amdgcn_readlane((int)(unsigned)(kk >> 32), 15);
    unsigned long long kmax = (((unsigned long long)khi) << 32) | klo;
    int ufi = 16384 - (int)(kmax & 0x7FFFull);
    cx = sx[ufi];                        // LDS broadcast (uniform)
    cy = pb[ufi*3+1];                    // uniform, L2-hot
    cz = pb[ufi*3+2];
  }
}

// ---------------------------------------------------------------------------
// Ball query: one wave per center. Ordered compaction of the first 32
// in-radius indices (ascending index order == jnp.sort-then-truncate).
// ---------------------------------------------------------------------------
__global__ __launch_bounds__(256) void ballq_kernel(const float* __restrict__ pos,
                                                    const float* __restrict__ centers,
                                                    int* __restrict__ idx){
#pragma clang fp contract(off)
  const float R2 = (float)(0.2*0.2);   // match Python double 0.2*0.2 -> f32
  int wid  = blockIdx.x*4 + (threadIdx.x >> 6);
  int lane = threadIdx.x & 63;
  int b = wid >> 10;                   // wid / S
  const float* pb = pos + (size_t)b * NPTS * 3;
  float cx = centers[wid*3+0], cy = centers[wid*3+1], cz = centers[wid*3+2];
  int* out = idx + wid*KNEI;
  int count = 0; int first = -1;
  for (int base = 0; base < NPTS; base += 64){
    int p = base + lane;
    float dx = pb[p*3+0]-cx, dy = pb[p*3+1]-cy, dz = pb[p*3+2]-cz;
    float t1 = dx*dx, t2 = dy*dy, t3 = dz*dz;
    float d = (t1 + t2) + t3;
    bool inr = d <= R2;
    unsigned long long mask = __ballot(inr);
    if (count == 0 && mask) first = base + __builtin_ctzll(mask);
    if (inr){
      int slot = count + __popcll(mask & ((1ull << lane) - 1ull));
      if (slot < KNEI) out[slot] = p;
    }
    count += __popcll(mask);
    if (count >= KNEI) break;
  }
  if (count < KNEI){
    for (int slot = count + lane; slot < KNEI; slot += 64) out[slot] = first;
  }
}

// ---------------------------------------------------------------------------
// GEMM1 sem: h1[m][0:64] = feat[b, idx[m], :] @ w(64x64) + bias.
// Block: 256 threads, 64-row tile. Also accumulates per-channel sum/sumsq.
// ---------------------------------------------------------------------------
__global__ __launch_bounds__(256) void gemm_sem1(const float* __restrict__ feat,
    const int* __restrict__ idx, const float* __restrict__ w,
    const float* __restrict__ bias, float* __restrict__ h1,
    float* __restrict__ stat){
  __shared__ float xs[64][68];
  __shared__ float wsh[64][64];
  const int tid = threadIdx.x;
  const int m0 = blockIdx.x * 64;
#pragma unroll
  for (int i = 0; i < 4; ++i){
    int q = tid + i*256;                 // 1024 quads of w (64x64)
    int r = q >> 4, c4 = q & 15;
    *(float4*)&wsh[r][c4*4] = *(const float4*)&w[r*64 + c4*4];
  }
#pragma unroll
  for (int i = 0; i < 4; ++i){
    int q = tid + i*256;                 // 1024 quads of x tile (64x64)
    int r = q >> 4, c4 = q & 15;
    int m = m0 + r;
    int nb = idx[m];
    int b = m >> 15;                     // m / (S*KNEI)
    const float* fr = feat + ((size_t)b*NPTS + nb)*64;
    *(float4*)&xs[r][c4*4] = *(const float4*)&fr[c4*4];
  }
  __syncthreads();
  const int g  = tid & 7;                // channel group: 8 channels
  const int rt = tid >> 3;               // 32 row-threads, 2 rows each
  const int r0 = rt * 2;
  float acc[2][8];
#pragma unroll
  for (int c = 0; c < 8; ++c){ float bb = bias[g*8+c]; acc[0][c] = bb; acc[1][c] = bb; }
  for (int k = 0; k < 64; ++k){
    float x0 = xs[r0][k], x1 = xs[r0+1][k];
    float4 wa = *(float4*)&wsh[k][g*8];
    float4 wb = *(float4*)&wsh[k][g*8+4];
    float wv[8] = {wa.x,wa.y,wa.z,wa.w,wb.x,wb.y,wb.z,wb.w};
#pragma unroll
    for (int c = 0; c < 8; ++c){ acc[0][c] += x0*wv[c]; acc[1][c] += x1*wv[c]; }
  }
#pragma unroll
  for (int r = 0; r < 2; ++r){
    float* dst = h1 + (size_t)(m0 + r0 + r)*64 + g*8;
    *(float4*)dst     = make_float4(acc[r][0],acc[r][1],acc[r][2],acc[r][3]);
    *(float4*)(dst+4) = make_float4(acc[r][4],acc[r][5],acc[r][6],acc[r][7]);
  }
  float ls[8], lq[8];
#pragma unroll
  for (int c = 0; c < 8; ++c){
    ls[c] = acc[0][c] + acc[1][c];
    lq[c] = acc[0][c]*acc[0][c] + acc[1][c]*acc[1][c];
  }
  __syncthreads();
  float* red  = &xs[0][0];
  float* redq = &wsh[0][0];
#pragma unroll
  for (int c = 0; c < 8; ++c){
    red[(g*8+c)*32 + rt]  = ls[c];
    redq[(g*8+c)*32 + rt] = lq[c];
  }
  __syncthreads();
  if (tid < 128){
    int c = tid & 63;
    const float* src = (tid < 64) ? red : redq;
    float a2 = 0.f;
    for (int i = 0; i < 32; ++i) a2 += src[c*32+i];
    atomicAdd(&stat[(tid < 64 ? 0 : 64) + c], a2);
  }
}

// ---------------------------------------------------------------------------
// GEMM2 (sem & geo layer 2): x = relu(a*hin+d) (folded BN1), out 128 ch.
// ---------------------------------------------------------------------------
__global__ __launch_bounds__(256) void gemm2_kernel(const float* __restrict__ hin,
    const float* __restrict__ abn, const float* __restrict__ dbn,
    const float* __restrict__ w, const float* __restrict__ bias,
    float* __restrict__ hout, float* __restrict__ stat){
  __shared__ float xs[64][68];
  __shared__ float wsh[64][128];
  const int tid = threadIdx.x;
  const int m0 = blockIdx.x * 64;
#pragma unroll
  for (int i = 0; i < 8; ++i){
    int q = tid + i*256;                 // 2048 quads of w (64x128)
    int r = q >> 5, c4 = q & 31;
    *(float4*)&wsh[r][c4*4] = *(const float4*)&w[r*128 + c4*4];
  }
#pragma unroll
  for (int i = 0; i < 4; ++i){
    int q = tid + i*256;
    int r = q >> 4, c4 = q & 15;
    float4 v  = *(const float4*)&hin[(size_t)(m0+r)*64 + c4*4];
    float4 av = *(const float4*)&abn[c4*4];
    float4 dv = *(const float4*)&dbn[c4*4];
    v.x = fmaxf(v.x*av.x + dv.x, 0.f);
    v.y = fmaxf(v.y*av.y + dv.y, 0.f);
    v.z = fmaxf(v.z*av.z + dv.z, 0.f);
    v.w = fmaxf(v.w*av.w + dv.w, 0.f);
    *(float4*)&xs[r][c4*4] = v;
  }
  __syncthreads();
  const int g  = tid & 15;               // 16 groups x 8 ch = 128
  const int rt = tid >> 4;               // 16 row-threads x 4 rows = 64
  const int r0 = rt * 4;
  float acc[4][8];
#pragma unroll
  for (int c = 0; c < 8; ++c){
    float bb = bias[g*8+c];
    acc[0][c]=bb; acc[1][c]=bb; acc[2][c]=bb; acc[3][c]=bb;
  }
  for (int k = 0; k < 64; ++k){
    float x0 = xs[r0][k], x1 = xs[r0+1][k], x2 = xs[r0+2][k], x3 = xs[r0+3][k];
    float4 wa = *(float4*)&wsh[k][g*8];
    float4 wb = *(float4*)&wsh[k][g*8+4];
    float wv[8] = {wa.x,wa.y,wa.z,wa.w,wb.x,wb.y,wb.z,wb.w};
#pragma unroll
    for (int c = 0; c < 8; ++c){
      acc[0][c] += x0*wv[c]; acc[1][c] += x1*wv[c];
      acc[2][c] += x2*wv[c]; acc[3][c] += x3*wv[c];
    }
  }
#pragma unroll
  for (int r = 0; r < 4; ++r){
    float* dst = hout + (size_t)(m0 + r0 + r)*128 + g*8;
    *(float4*)dst     = make_float4(acc[r][0],acc[r][1],acc[r][2],acc[r][3]);
    *(float4*)(dst+4) = make_float4(acc[r][4],acc[r][5],acc[r][6],acc[r][7]);
  }
  float ls[8], lq[8];
#pragma unroll
  for (int c = 0; c < 8; ++c){
    ls[c] = acc[0][c]+acc[1][c]+acc[2][c]+acc[3][c];
    lq[c] = acc[0][c]*acc[0][c]+acc[1][c]*acc[1][c]+acc[2][c]*acc[2][c]+acc[3][c]*acc[3][c];
  }
  __syncthreads();
  float* red = &xs[0][0];                // 2048 sums + 2048 sumsq (fits 64*68)
#pragma unroll
  for (int c = 0; c < 8; ++c){
    red[(g*8+c)*16 + rt]        = ls[c];
    red[2048 + (g*8+c)*16 + rt] = lq[c];
  }
  __syncthreads();
  {
    int c = tid & 127;
    int isq = tid >> 7;
    float a2 = 0.f;
    for (int i = 0; i < 16; ++i) a2 += red[isq*2048 + c*16 + i];
    atomicAdd(&stat[isq*128 + c], a2);
  }
}

// ---------------------------------------------------------------------------
// GEMM1 geo: x = [center(3) | grouped_pos(3)] (6 ch) @ w(6x64) + bias.
// ---------------------------------------------------------------------------
__global__ __launch_bounds__(256) void gemm_geo1(const float* __restrict__ pos,
    const float* __restrict__ centers, const int* __restrict__ idx,
    const float* __restrict__ w, const float* __restrict__ bias,
    float* __restrict__ hout, float* __restrict__ stat){
  __shared__ float xs[64][8];
  __shared__ float wsh[6][64];
  __shared__ float red[2048];
  __shared__ float redq[2048];
  const int tid = threadIdx.x;
  const int m0 = blockIdx.x * 64;
  for (int i = tid; i < 384; i += 256) wsh[i >> 6][i & 63] = w[i];
  if (tid < 64){
    int m = m0 + tid;
    int grp = m >> 5;                    // m / KNEI
    int b = m >> 15;
    int nb = idx[m];
    const float* cp = centers + (size_t)grp*3;
    const float* pp = pos + ((size_t)b*NPTS + nb)*3;
    xs[tid][0]=cp[0]; xs[tid][1]=cp[1]; xs[tid][2]=cp[2];
    xs[tid][3]=pp[0]; xs[tid][4]=pp[1]; xs[tid][5]=pp[2];
  }
  __syncthreads();
  const int g  = tid & 7;
  const int rt = tid >> 3;
  const int r0 = rt * 2;
  float acc[2][8];
#pragma unroll
  for (int c = 0; c < 8; ++c){ float bb = bias[g*8+c]; acc[0][c]=bb; acc[1][c]=bb; }
#pragma unroll
  for (int k = 0; k < 6; ++k){
    float x0 = xs[r0][k], x1 = xs[r0+1][k];
    float4 wa = *(float4*)&wsh[k][g*8];
    float4 wb = *(float4*)&wsh[k][g*8+4];
    float wv[8] = {wa.x,wa.y,wa.z,wa.w,wb.x,wb.y,wb.z,wb.w};
#pragma unroll
    for (int c = 0; c < 8; ++c){ acc[0][c] += x0*wv[c]; acc[1][c] += x1*wv[c]; }
  }
#pragma unroll
  for (int r = 0; r < 2; ++r){
    float* dst = hout + (size_t)(m0 + r0 + r)*64 + g*8;
    *(float4*)dst     = make_float4(acc[r][0],acc[r][1],acc[r][2],acc[r][3]);
    *(float4*)(dst+4) = make_float4(acc[r][4],acc[r][5],acc[r][6],acc[r][7]);
  }
  float ls[8], lq[8];
#pragma unroll
  for (int c = 0; c < 8; ++c){
    ls[c] = acc[0][c] + acc[1][c];
    lq[c] = acc[0][c]*acc[0][c] + acc[1][c]*acc[1][c];
  }
#pragma unroll
  for (int c = 0; c < 8; ++c){
    red[(g*8+c)*32 + rt]  = ls[c];
    redq[(g*8+c)*32 + rt] = lq[c];
  }
  __syncthreads();
  if (tid < 128){
    int c = tid & 63;
    const float* src = (tid < 64) ? red : redq;
    float a2 = 0.f;
    for (int i = 0; i < 32; ++i) a2 += src[c*32+i];
    atomicAdd(&stat[(tid < 64 ? 0 : 64) + c], a2);
  }
}

// ---------------------------------------------------------------------------
// BN finalize: fold stats into per-channel scale/shift a,d.
// ---------------------------------------------------------------------------
__global__ void bn_finalize(const float* __restrict__ stat,
                            const float* __restrict__ gam, const float* __restrict__ bet,
                            float* __restrict__ a, float* __restrict__ d, int C){
  int c = threadIdx.x;
  if (c >= C) return;
  const float invM = 1.0f / (float)MROWS;
  float mu  = stat[c] * invM;
  float ex2 = stat[C + c] * invM;
  float var = ex2 - mu*mu;
  float aa = gam[c] * rsqrtf(var + 1e-5f);
  a[c] = aa;
  d[c] = bet[c] - mu*aa;
}

// ---------------------------------------------------------------------------
// Max over K with folded BN2 + ReLU: out[grp][c] = relu(max_k (a*h+d)).
// ---------------------------------------------------------------------------
__global__ __launch_bounds__(256) void maxpool_kernel(const float* __restrict__ hin,
    const float* __restrict__ abn, const float* __restrict__ dbn,
    float* __restrict__ out){
  const int tid = threadIdx.x;
  const int grp = blockIdx.x*8 + (tid >> 5);
  const int c4 = tid & 31;
  const float* base = hin + (size_t)grp*KNEI*128 + c4*4;
  float4 a = *(const float4*)&abn[c4*4];
  float4 d = *(const float4*)&dbn[c4*4];
  float4 m = make_float4(-3.4e38f,-3.4e38f,-3.4e38f,-3.4e38f);
  for (int k = 0; k < KNEI; ++k){
    float4 v = *(const float4*)&base[(size_t)k*128];
    m.x = fmaxf(m.x, v.x*a.x + d.x);
    m.y = fmaxf(m.y, v.y*a.y + d.y);
    m.z = fmaxf(m.z, v.z*a.z + d.z);
    m.w = fmaxf(m.w, v.w*a.w + d.w);
  }
  m.x = fmaxf(m.x, 0.f); m.y = fmaxf(m.y, 0.f);
  m.z = fmaxf(m.z, 0.f); m.w = fmaxf(m.w, 0.f);
  *(float4*)&out[(size_t)grp*128 + c4*4] = m;
}

__global__ void zero_kernel(float* __restrict__ p, int n){
  int i = blockIdx.x*blockDim.x + threadIdx.x;
  if (i < n) p[i] = 0.f;
}

extern "C" void kernel_launch(void* const* d_in, const int* in_sizes, int n_in,
                              void* d_out, int out_size, void* d_ws, size_t ws_size,
                              hipStream_t stream){
  const float* pos   = (const float*)d_in[0];
  const float* feat  = (const float*)d_in[1];
  const float* w_s1  = (const float*)d_in[2];
  const float* b_s1  = (const float*)d_in[3];
  const float* g_s1  = (const float*)d_in[4];
  const float* be_s1 = (const float*)d_in[5];
  const float* w_s2  = (const float*)d_in[6];
  const float* b_s2  = (const float*)d_in[7];
  const float* g_s2  = (const float*)d_in[8];
  const float* be_s2 = (const float*)d_in[9];
  const float* w_g1  = (const float*)d_in[10];
  const float* b_g1  = (const float*)d_in[11];
  const float* g_g1  = (const float*)d_in[12];
  const float* be_g1 = (const float*)d_in[13];
  const float* w_g2  = (const float*)d_in[14];
  const float* b_g2  = (const float*)d_in[15];
  const float* g_g2  = (const float*)d_in[16];
  const float* be_g2 = (const float*)d_in[17];
  float* outp = (float*)d_out;
  float* wsf  = (float*)d_ws;

  // workspace layout (floats):
  float* centers = wsf;                         // 8192*3 = 24576
  int*   idxp    = (int*)(wsf + 24576);         // 262144
  float* stats   = wsf + 24576 + 262144;        // 768
  float* bnad    = stats + 768;                 // 768
  float* h1      = wsf + 288256;                // 262144*64
  float* h2      = h1 + (size_t)MROWS*64;       // 262144*128
  // total = 50,619,904 floats = ~193.1 MiB

  float* st1 = stats;        // 64 sum + 64 sq
  float* st2 = stats + 128;  // 128 + 128
  float* st3 = stats + 384;  // 64 + 64
  float* st4 = stats + 512;  // 128 + 128
  float* a1 = bnad;        float* d1 = bnad + 64;
  float* a2 = bnad + 128;  float* d2 = bnad + 256;
  float* a3 = bnad + 384;  float* d3 = bnad + 448;
  float* a4 = bnad + 512;  float* d4 = bnad + 640;

  // allow >64 KiB dynamic LDS for fps_kernel (idempotent)
  hipFuncSetAttribute((const void*)fps_kernel,
                      hipFuncAttributeMaxDynamicSharedMemorySize,
                      FPS_LDS_BYTES);

  zero_kernel<<<3, 256, 0, stream>>>(stats, 768);
  fps_kernel<<<NB, 1024, FPS_LDS_BYTES, stream>>>(pos, centers);
  ballq_kernel<<<(NB*S)/4, 256, 0, stream>>>(pos, centers, idxp);

  // sem branch
  gemm_sem1<<<MROWS/64, 256, 0, stream>>>(feat, idxp, w_s1, b_s1, h1, st1);
  bn_finalize<<<1, 128, 0, stream>>>(st1, g_s1, be_s1, a1, d1, 64);
  gemm2_kernel<<<MROWS/64, 256, 0, stream>>>(h1, a1, d1, w_s2, b_s2, h2, st2);
  bn_finalize<<<1, 128, 0, stream>>>(st2, g_s2, be_s2, a2, d2, 128);
  maxpool_kernel<<<(NB*S)/8, 256, 0, stream>>>(h2, a2, d2, outp);

  // geo branch (reuses h1/h2)
  gemm_geo1<<<MROWS/64, 256, 0, stream>>>(pos, centers, idxp, w_g1, b_g1, h1, st3);
  bn_finalize<<<1, 128, 0, stream>>>(st3, g_g1, be_g1, a3, d3, 64);
  gemm2_kernel<<<MROWS/64, 256, 0, stream>>>(h1, a3, d3, w_g2, b_g2, h2, st4);
  bn_finalize<<<1, 128, 0, stream>>>(st4, g_g2, be_g2, a4, d4, 128);
  maxpool_kernel<<<(NB*S)/8, 256, 0, stream>>>(h2, a4, d4, outp + (size_t)NB*S*128);
}

// Round 4
// 2158.909 us; speedup vs baseline: 10.9318x; 1.0280x over previous
//
#include <hip/hip_runtime.h>

#define NB 8
#define NPTS 16384
#define S 1024
#define KNEI 32
#define MROWS (NB*S*KNEI)   // 262144

typedef float v2f __attribute__((ext_vector_type(2)));

// Value-only max combine via DPP, bound_ctrl=1 (invalid lanes read 0 --
// safe identity: all reduced values are >= 0).
#define DPP_MAXF0(CTRL, v) do {                                               \
    int _o = __builtin_amdgcn_update_dpp(0, __float_as_int(v),                \
                                         (CTRL), 0xF, 0xF, true);             \
    (v) = fmaxf((v), __int_as_float(_o));                                     \
  } while (0)

// u64 key max combine via DPP halves, bound_ctrl=1 (identity 0 always loses:
// every real key >= 1 because of the 16384-idx field).
#define DPP_MAXK0(CTRL, k) do {                                               \
    int _olo = __builtin_amdgcn_update_dpp(0, (int)(unsigned)(k),             \
                                           (CTRL), 0xF, 0xF, true);           \
    int _ohi = __builtin_amdgcn_update_dpp(0, (int)(unsigned)((k) >> 32),     \
                                           (CTRL), 0xF, 0xF, true);           \
    unsigned long long _ok = (((unsigned long long)(unsigned)_ohi) << 32)     \
                           | (unsigned)_olo;                                  \
    if (_ok > (k)) (k) = _ok;                                                 \
  } while (0)

#define DPP_ROW_SHR1   0x111
#define DPP_ROW_SHR2   0x112
#define DPP_ROW_SHR4   0x114
#define DPP_ROW_SHR8   0x118
#define DPP_ROW_BCAST15 0x142
#define DPP_ROW_BCAST31 0x143

// ---------------------------------------------------------------------------
// FPS r13: r10/r12 were secretly SCRATCH-SPILL loops. VGPR_Count=40 while the
// design needs >=64 floats of per-thread state: __launch_bounds__(1024) with
// no min-waves arg let the compiler target high occupancy (~40-VGPR budget)
// and spill px/py/pz/dist to scratch, reloading ~320KB/step through L1 --
// that, not VALU issue, set the 3653 cyc/step floor. Fix:
//   __launch_bounds__(1024, 4): 16 waves = 4 waves/SIMD -> 128-VGPR budget;
//   state (~95 regs) now fits with zero spill.
// Pressure trims so RA definitely fits: single merged distance pass (no
// dxx[8] array); no LDS x-plane -- the winner's coords come from one uniform
// (SGPR) load of pb[ufi*3..] (read-only data, constant-cache safe); LDS is
// just 2x16 u64 key slots (static, 256 B).
// Reduce (unchanged from r12, verified): wave f32 DPP max -> in-wave locate
// scan (exact bit-equality, first occurrence) -> u64 key
// (dist_bits<<15 | 16384-idx) -> one barrier -> 16-slot u64 DPP reduce.
// Exact-match discipline: no fp contraction, ((dx^2+dy^2)+dz^2) order,
// first-occurrence argmax via complemented-index key field.
// ---------------------------------------------------------------------------
__global__ __launch_bounds__(1024, 4) void fps_kernel(const float* __restrict__ pos,
                                                      float* __restrict__ centers){
#pragma clang fp contract(off)
  __shared__ unsigned long long lslot[2][16];
  const int b = blockIdx.x;
  const int t = threadIdx.x;
  const int wid = t >> 6, lane = t & 63;
  const float* pb = pos + (size_t)b * NPTS * 3;
  const int p0 = t * 16;                 // this thread's first point index

  v2f px[8], py[8], pz[8], dist[8];
  {
    float c[48];
    const float4* src = (const float4*)(pb + (size_t)t*48);
#pragma unroll
    for (int q = 0; q < 12; ++q) *(float4*)&c[q*4] = src[q];
#pragma unroll
    for (int j = 0; j < 8; ++j){
      px[j] = (v2f){c[6*j+0], c[6*j+3]};
      py[j] = (v2f){c[6*j+1], c[6*j+4]};
      pz[j] = (v2f){c[6*j+2], c[6*j+5]};
    }
  }
#pragma unroll
  for (int j = 0; j < 8; ++j){
    asm volatile("" : "+v"(px[j]), "+v"(py[j]), "+v"(pz[j]));  // no remat
    dist[j] = (v2f){1e10f, 1e10f};
  }
  float cx = pb[0], cy = pb[1], cz = pb[2];    // far=0 initial centroid

  for (int s = 0; s < S; ++s){
    if (t == 0){
      float* cd = centers + (size_t)(b*S + s)*3;
      cd[0] = cx; cd[1] = cy; cd[2] = cz;
    }
    float bv = 0.0f;
    {
      v2f cx2 = (v2f){cx, cx}, cy2 = (v2f){cy, cy}, cz2 = (v2f){cz, cz};
#pragma unroll
      for (int j = 0; j < 8; ++j){
        v2f dx = px[j] - cx2;
        v2f dy = py[j] - cy2;
        v2f dz = pz[j] - cz2;
        v2f t1 = dx * dx;
        v2f t2 = dy * dy;
        v2f t3 = dz * dz;
        v2f d  = (t1 + t2) + t3;         // ((dx^2+dy^2)+dz^2)
        v2f od = dist[j];
        v2f nd = (v2f){__builtin_fminf(od.x, d.x), __builtin_fminf(od.y, d.y)};
        dist[j] = nd;
        bv = fmaxf(fmaxf(bv, nd.x), nd.y);   // v_max3
      }
    }
    // wave-level value max (DPP)
    DPP_MAXF0(DPP_ROW_SHR1,   bv);
    DPP_MAXF0(DPP_ROW_SHR2,   bv);
    DPP_MAXF0(DPP_ROW_SHR4,   bv);
    DPP_MAXF0(DPP_ROW_SHR8,   bv);
    DPP_MAXF0(DPP_ROW_BCAST15, bv);
    DPP_MAXF0(DPP_ROW_BCAST31, bv);   // lane 63 = wave max
    float bm = __int_as_float(
        __builtin_amdgcn_readlane(__float_as_int(bv), 63));
    // smallest local j with dist[j]==bm (bit-copy => exact equality)
    int bj = 16;
#pragma unroll
    for (int j = 7; j >= 0; --j){
      if (dist[j].y == bm) bj = 2*j+1;
      if (dist[j].x == bm) bj = 2*j;
    }
    unsigned long long mk = __ballot(bj < 16);    // nonzero: bm is in-wave
    int l0 = (int)__builtin_ctzll(mk);            // lowest lane = smallest idx
    int wc = __builtin_amdgcn_readlane(p0 + bj, l0);
    const int par = s & 1;
    if (lane == 0){
      lslot[par][wid] = ((unsigned long long)__float_as_uint(bm) << 15)
                      | (unsigned long long)(16384 - wc);
    }
    __syncthreads();
    // cross-wave u64 reduce: 16 slots on lanes 0-15 of each row
    unsigned long long kk = lslot[par][lane & 15];
    DPP_MAXK0(DPP_ROW_SHR1, kk);
    DPP_MAXK0(DPP_ROW_SHR2, kk);
    DPP_MAXK0(DPP_ROW_SHR4, kk);
    DPP_MAXK0(DPP_ROW_SHR8, kk);
    unsigned klo = (unsigned)__builtin_amdgcn_readlane((int)(unsigned)kk, 15);
    unsigned khi = (unsigned)__builtin_amdgcn_readlane((int)(unsigned)(kk >> 32), 15);
    unsigned long long kmax = (((unsigned long long)khi) << 32) | klo;
    int ufi = 16384 - (int)(kmax & 0x7FFFull);
    const float* cp = pb + (size_t)ufi*3;   // uniform (SGPR) -> s_load, L2-hot
    cx = cp[0]; cy = cp[1]; cz = cp[2];
  }
}

// ---------------------------------------------------------------------------
// Ball query: one wave per center. Ordered compaction of the first 32
// in-radius indices (ascending index order == jnp.sort-then-truncate).
// ---------------------------------------------------------------------------
__global__ __launch_bounds__(256) void ballq_kernel(const float* __restrict__ pos,
                                                    const float* __restrict__ centers,
                                                    int* __restrict__ idx){
#pragma clang fp contract(off)
  const float R2 = (float)(0.2*0.2);   // match Python double 0.2*0.2 -> f32
  int wid  = blockIdx.x*4 + (threadIdx.x >> 6);
  int lane = threadIdx.x & 63;
  int b = wid >> 10;                   // wid / S
  const float* pb = pos + (size_t)b * NPTS * 3;
  float cx = centers[wid*3+0], cy = centers[wid*3+1], cz = centers[wid*3+2];
  int* out = idx + wid*KNEI;
  int count = 0; int first = -1;
  for (int base = 0; base < NPTS; base += 64){
    int p = base + lane;
    float dx = pb[p*3+0]-cx, dy = pb[p*3+1]-cy, dz = pb[p*3+2]-cz;
    float t1 = dx*dx, t2 = dy*dy, t3 = dz*dz;
    float d = (t1 + t2) + t3;
    bool inr = d <= R2;
    unsigned long long mask = __ballot(inr);
    if (count == 0 && mask) first = base + __builtin_ctzll(mask);
    if (inr){
      int slot = count + __popcll(mask & ((1ull << lane) - 1ull));
      if (slot < KNEI) out[slot] = p;
    }
    count += __popcll(mask);
    if (count >= KNEI) break;
  }
  if (count < KNEI){
    for (int slot = count + lane; slot < KNEI; slot += 64) out[slot] = first;
  }
}

// ---------------------------------------------------------------------------
// GEMM1 sem: h1[m][0:64] = feat[b, idx[m], :] @ w(64x64) + bias.
// Block: 256 threads, 64-row tile. Also accumulates per-channel sum/sumsq.
// ---------------------------------------------------------------------------
__global__ __launch_bounds__(256) void gemm_sem1(const float* __restrict__ feat,
    const int* __restrict__ idx, const float* __restrict__ w,
    const float* __restrict__ bias, float* __restrict__ h1,
    float* __restrict__ stat){
  __shared__ float xs[64][68];
  __shared__ float wsh[64][64];
  const int tid = threadIdx.x;
  const int m0 = blockIdx.x * 64;
#pragma unroll
  for (int i = 0; i < 4; ++i){
    int q = tid + i*256;                 // 1024 quads of w (64x64)
    int r = q >> 4, c4 = q & 15;
    *(float4*)&wsh[r][c4*4] = *(const float4*)&w[r*64 + c4*4];
  }
#pragma unroll
  for (int i = 0; i < 4; ++i){
    int q = tid + i*256;                 // 1024 quads of x tile (64x64)
    int r = q >> 4, c4 = q & 15;
    int m = m0 + r;
    int nb = idx[m];
    int b = m >> 15;                     // m / (S*KNEI)
    const float* fr = feat + ((size_t)b*NPTS + nb)*64;
    *(float4*)&xs[r][c4*4] = *(const float4*)&fr[c4*4];
  }
  __syncthreads();
  const int g  = tid & 7;                // channel group: 8 channels
  const int rt = tid >> 3;               // 32 row-threads, 2 rows each
  const int r0 = rt * 2;
  float acc[2][8];
#pragma unroll
  for (int c = 0; c < 8; ++c){ float bb = bias[g*8+c]; acc[0][c] = bb; acc[1][c] = bb; }
  for (int k = 0; k < 64; ++k){
    float x0 = xs[r0][k], x1 = xs[r0+1][k];
    float4 wa = *(float4*)&wsh[k][g*8];
    float4 wb = *(float4*)&wsh[k][g*8+4];
    float wv[8] = {wa.x,wa.y,wa.z,wa.w,wb.x,wb.y,wb.z,wb.w};
#pragma unroll
    for (int c = 0; c < 8; ++c){ acc[0][c] += x0*wv[c]; acc[1][c] += x1*wv[c]; }
  }
#pragma unroll
  for (int r = 0; r < 2; ++r){
    float* dst = h1 + (size_t)(m0 + r0 + r)*64 + g*8;
    *(float4*)dst     = make_float4(acc[r][0],acc[r][1],acc[r][2],acc[r][3]);
    *(float4*)(dst+4) = make_float4(acc[r][4],acc[r][5],acc[r][6],acc[r][7]);
  }
  float ls[8], lq[8];
#pragma unroll
  for (int c = 0; c < 8; ++c){
    ls[c] = acc[0][c] + acc[1][c];
    lq[c] = acc[0][c]*acc[0][c] + acc[1][c]*acc[1][c];
  }
  __syncthreads();
  float* red  = &xs[0][0];
  float* redq = &wsh[0][0];
#pragma unroll
  for (int c = 0; c < 8; ++c){
    red[(g*8+c)*32 + rt]  = ls[c];
    redq[(g*8+c)*32 + rt] = lq[c];
  }
  __syncthreads();
  if (tid < 128){
    int c = tid & 63;
    const float* src = (tid < 64) ? red : redq;
    float a2 = 0.f;
    for (int i = 0; i < 32; ++i) a2 += src[c*32+i];
    atomicAdd(&stat[(tid < 64 ? 0 : 64) + c], a2);
  }
}

// ---------------------------------------------------------------------------
// GEMM2 (sem & geo layer 2): x = relu(a*hin+d) (folded BN1), out 128 ch.
// ---------------------------------------------------------------------------
__global__ __launch_bounds__(256) void gemm2_kernel(const float* __restrict__ hin,
    const float* __restrict__ abn, const float* __restrict__ dbn,
    const float* __restrict__ w, const float* __restrict__ bias,
    float* __restrict__ hout, float* __restrict__ stat){
  __shared__ float xs[64][68];
  __shared__ float wsh[64][128];
  const int tid = threadIdx.x;
  const int m0 = blockIdx.x * 64;
#pragma unroll
  for (int i = 0; i < 8; ++i){
    int q = tid + i*256;                 // 2048 quads of w (64x128)
    int r = q >> 5, c4 = q & 31;
    *(float4*)&wsh[r][c4*4] = *(const float4*)&w[r*128 + c4*4];
  }
#pragma unroll
  for (int i = 0; i < 4; ++i){
    int q = tid + i*256;
    int r = q >> 4, c4 = q & 15;
    float4 v  = *(const float4*)&hin[(size_t)(m0+r)*64 + c4*4];
    float4 av = *(const float4*)&abn[c4*4];
    float4 dv = *(const float4*)&dbn[c4*4];
    v.x = fmaxf(v.x*av.x + dv.x, 0.f);
    v.y = fmaxf(v.y*av.y + dv.y, 0.f);
    v.z = fmaxf(v.z*av.z + dv.z, 0.f);
    v.w = fmaxf(v.w*av.w + dv.w, 0.f);
    *(float4*)&xs[r][c4*4] = v;
  }
  __syncthreads();
  const int g  = tid & 15;               // 16 groups x 8 ch = 128
  const int rt = tid >> 4;               // 16 row-threads x 4 rows = 64
  const int r0 = rt * 4;
  float acc[4][8];
#pragma unroll
  for (int c = 0; c < 8; ++c){
    float bb = bias[g*8+c];
    acc[0][c]=bb; acc[1][c]=bb; acc[2][c]=bb; acc[3][c]=bb;
  }
  for (int k = 0; k < 64; ++k){
    float x0 = xs[r0][k], x1 = xs[r0+1][k], x2 = xs[r0+2][k], x3 = xs[r0+3][k];
    float4 wa = *(float4*)&wsh[k][g*8];
    float4 wb = *(float4*)&wsh[k][g*8+4];
    float wv[8] = {wa.x,wa.y,wa.z,wa.w,wb.x,wb.y,wb.z,wb.w};
#pragma unroll
    for (int c = 0; c < 8; ++c){
      acc[0][c] += x0*wv[c]; acc[1][c] += x1*wv[c];
      acc[2][c] += x2*wv[c]; acc[3][c] += x3*wv[c];
    }
  }
#pragma unroll
  for (int r = 0; r < 4; ++r){
    float* dst = hout + (size_t)(m0 + r0 + r)*128 + g*8;
    *(float4*)dst     = make_float4(acc[r][0],acc[r][1],acc[r][2],acc[r][3]);
    *(float4*)(dst+4) = make_float4(acc[r][4],acc[r][5],acc[r][6],acc[r][7]);
  }
  float ls[8], lq[8];
#pragma unroll
  for (int c = 0; c < 8; ++c){
    ls[c] = acc[0][c]+acc[1][c]+acc[2][c]+acc[3][c];
    lq[c] = acc[0][c]*acc[0][c]+acc[1][c]*acc[1][c]+acc[2][c]*acc[2][c]+acc[3][c]*acc[3][c];
  }
  __syncthreads();
  float* red = &xs[0][0];                // 2048 sums + 2048 sumsq (fits 64*68)
#pragma unroll
  for (int c = 0; c < 8; ++c){
    red[(g*8+c)*16 + rt]        = ls[c];
    red[2048 + (g*8+c)*16 + rt] = lq[c];
  }
  __syncthreads();
  {
    int c = tid & 127;
    int isq = tid >> 7;
    float a2 = 0.f;
    for (int i = 0; i < 16; ++i) a2 += red[isq*2048 + c*16 + i];
    atomicAdd(&stat[isq*128 + c], a2);
  }
}

// ---------------------------------------------------------------------------
// GEMM1 geo: x = [center(3) | grouped_pos(3)] (6 ch) @ w(6x64) + bias.
// ---------------------------------------------------------------------------
__global__ __launch_bounds__(256) void gemm_geo1(const float* __restrict__ pos,
    const float* __restrict__ centers, const int* __restrict__ idx,
    const float* __restrict__ w, const float* __restrict__ bias,
    float* __restrict__ hout, float* __restrict__ stat){
  __shared__ float xs[64][8];
  __shared__ float wsh[6][64];
  __shared__ float red[2048];
  __shared__ float redq[2048];
  const int tid = threadIdx.x;
  const int m0 = blockIdx.x * 64;
  for (int i = tid; i < 384; i += 256) wsh[i >> 6][i & 63] = w[i];
  if (tid < 64){
    int m = m0 + tid;
    int grp = m >> 5;                    // m / KNEI
    int b = m >> 15;
    int nb = idx[m];
    const float* cp = centers + (size_t)grp*3;
    const float* pp = pos + ((size_t)b*NPTS + nb)*3;
    xs[tid][0]=cp[0]; xs[tid][1]=cp[1]; xs[tid][2]=cp[2];
    xs[tid][3]=pp[0]; xs[tid][4]=pp[1]; xs[tid][5]=pp[2];
  }
  __syncthreads();
  const int g  = tid & 7;
  const int rt = tid >> 3;
  const int r0 = rt * 2;
  float acc[2][8];
#pragma unroll
  for (int c = 0; c < 8; ++c){ float bb = bias[g*8+c]; acc[0][c]=bb; acc[1][c]=bb; }
#pragma unroll
  for (int k = 0; k < 6; ++k){
    float x0 = xs[r0][k], x1 = xs[r0+1][k];
    float4 wa = *(float4*)&wsh[k][g*8];
    float4 wb = *(float4*)&wsh[k][g*8+4];
    float wv[8] = {wa.x,wa.y,wa.z,wa.w,wb.x,wb.y,wb.z,wb.w};
#pragma unroll
    for (int c = 0; c < 8; ++c){ acc[0][c] += x0*wv[c]; acc[1][c] += x1*wv[c]; }
  }
#pragma unroll
  for (int r = 0; r < 2; ++r){
    float* dst = hout + (size_t)(m0 + r0 + r)*64 + g*8;
    *(float4*)dst     = make_float4(acc[r][0],acc[r][1],acc[r][2],acc[r][3]);
    *(float4*)(dst+4) = make_float4(acc[r][4],acc[r][5],acc[r][6],acc[r][7]);
  }
  float ls[8], lq[8];
#pragma unroll
  for (int c = 0; c < 8; ++c){
    ls[c] = acc[0][c] + acc[1][c];
    lq[c] = acc[0][c]*acc[0][c] + acc[1][c]*acc[1][c];
  }
#pragma unroll
  for (int c = 0; c < 8; ++c){
    red[(g*8+c)*32 + rt]  = ls[c];
    redq[(g*8+c)*32 + rt] = lq[c];
  }
  __syncthreads();
  if (tid < 128){
    int c = tid & 63;
    const float* src = (tid < 64) ? red : redq;
    float a2 = 0.f;
    for (int i = 0; i < 32; ++i) a2 += src[c*32+i];
    atomicAdd(&stat[(tid < 64 ? 0 : 64) + c], a2);
  }
}

// ---------------------------------------------------------------------------
// BN finalize: fold stats into per-channel scale/shift a,d.
// ---------------------------------------------------------------------------
__global__ void bn_finalize(const float* __restrict__ stat,
                            const float* __restrict__ gam, const float* __restrict__ bet,
                            float* __restrict__ a, float* __restrict__ d, int C){
  int c = threadIdx.x;
  if (c >= C) return;
  const float invM = 1.0f / (float)MROWS;
  float mu  = stat[c] * invM;
  float ex2 = stat[C + c] * invM;
  float var = ex2 - mu*mu;
  float aa = gam[c] * rsqrtf(var + 1e-5f);
  a[c] = aa;
  d[c] = bet[c] - mu*aa;
}

// ---------------------------------------------------------------------------
// Max over K with folded BN2 + ReLU: out[grp][c] = relu(max_k (a*h+d)).
// ---------------------------------------------------------------------------
__global__ __launch_bounds__(256) void maxpool_kernel(const float* __restrict__ hin,
    const float* __restrict__ abn, const float* __restrict__ dbn,
    float* __restrict__ out){
  const int tid = threadIdx.x;
  const int grp = blockIdx.x*8 + (tid >> 5);
  const int c4 = tid & 31;
  const float* base = hin + (size_t)grp*KNEI*128 + c4*4;
  float4 a = *(const float4*)&abn[c4*4];
  float4 d = *(const float4*)&dbn[c4*4];
  float4 m = make_float4(-3.4e38f,-3.4e38f,-3.4e38f,-3.4e38f);
  for (int k = 0; k < KNEI; ++k){
    float4 v = *(const float4*)&base[(size_t)k*128];
    m.x = fmaxf(m.x, v.x*a.x + d.x);
    m.y = fmaxf(m.y, v.y*a.y + d.y);
    m.z = fmaxf(m.z, v.z*a.z + d.z);
    m.w = fmaxf(m.w, v.w*a.w + d.w);
  }
  m.x = fmaxf(m.x, 0.f); m.y = fmaxf(m.y, 0.f);
  m.z = fmaxf(m.z, 0.f); m.w = fmaxf(m.w, 0.f);
  *(float4*)&out[(size_t)grp*128 + c4*4] = m;
}

__global__ void zero_kernel(float* __restrict__ p, int n){
  int i = blockIdx.x*blockDim.x + threadIdx.x;
  if (i < n) p[i] = 0.f;
}

extern "C" void kernel_launch(void* const* d_in, const int* in_sizes, int n_in,
                              void* d_out, int out_size, void* d_ws, size_t ws_size,
                              hipStream_t stream){
  const float* pos   = (const float*)d_in[0];
  const float* feat  = (const float*)d_in[1];
  const float* w_s1  = (const float*)d_in[2];
  const float* b_s1  = (const float*)d_in[3];
  const float* g_s1  = (const float*)d_in[4];
  const float* be_s1 = (const float*)d_in[5];
  const float* w_s2  = (const float*)d_in[6];
  const float* b_s2  = (const float*)d_in[7];
  const float* g_s2  = (const float*)d_in[8];
  const float* be_s2 = (const float*)d_in[9];
  const float* w_g1  = (const float*)d_in[10];
  const float* b_g1  = (const float*)d_in[11];
  const float* g_g1  = (const float*)d_in[12];
  const float* be_g1 = (const float*)d_in[13];
  const float* w_g2  = (const float*)d_in[14];
  const float* b_g2  = (const float*)d_in[15];
  const float* g_g2  = (const float*)d_in[16];
  const float* be_g2 = (const float*)d_in[17];
  float* outp = (float*)d_out;
  float* wsf  = (float*)d_ws;

  // workspace layout (floats):
  float* centers = wsf;                         // 8192*3 = 24576
  int*   idxp    = (int*)(wsf + 24576);         // 262144
  float* stats   = wsf + 24576 + 262144;        // 768
  float* bnad    = stats + 768;                 // 768
  float* h1      = wsf + 288256;                // 262144*64
  float* h2      = h1 + (size_t)MROWS*64;       // 262144*128
  // total = 50,619,904 floats = ~193.1 MiB

  float* st1 = stats;        // 64 sum + 64 sq
  float* st2 = stats + 128;  // 128 + 128
  float* st3 = stats + 384;  // 64 + 64
  float* st4 = stats + 512;  // 128 + 128
  float* a1 = bnad;        float* d1 = bnad + 64;
  float* a2 = bnad + 128;  float* d2 = bnad + 256;
  float* a3 = bnad + 384;  float* d3 = bnad + 448;
  float* a4 = bnad + 512;  float* d4 = bnad + 640;

  zero_kernel<<<3, 256, 0, stream>>>(stats, 768);
  fps_kernel<<<NB, 1024, 0, stream>>>(pos, centers);
  ballq_kernel<<<(NB*S)/4, 256, 0, stream>>>(pos, centers, idxp);

  // sem branch
  gemm_sem1<<<MROWS/64, 256, 0, stream>>>(feat, idxp, w_s1, b_s1, h1, st1);
  bn_finalize<<<1, 128, 0, stream>>>(st1, g_s1, be_s1, a1, d1, 64);
  gemm2_kernel<<<MROWS/64, 256, 0, stream>>>(h1, a1, d1, w_s2, b_s2, h2, st2);
  bn_finalize<<<1, 128, 0, stream>>>(st2, g_s2, be_s2, a2, d2, 128);
  maxpool_kernel<<<(NB*S)/8, 256, 0, stream>>>(h2, a2, d2, outp);

  // geo branch (reuses h1/h2)
  gemm_geo1<<<MROWS/64, 256, 0, stream>>>(pos, centers, idxp, w_g1, b_g1, h1, st3);
  bn_finalize<<<1, 128, 0, stream>>>(st3, g_g1, be_g1, a3, d3, 64);
  gemm2_kernel<<<MROWS/64, 256, 0, stream>>>(h1, a3, d3, w_g2, b_g2, h2, st4);
  bn_finalize<<<1, 128, 0, stream>>>(st4, g_g2, be_g2, a4, d4, 128);
  maxpool_kernel<<<(NB*S)/8, 256, 0, stream>>>(h2, a4, d4, outp + (size_t)NB*S*128);
}

// Round 5
// 1958.738 us; speedup vs baseline: 12.0490x; 1.1022x over previous
//
#include <hip/hip_runtime.h>

#define NB 8
#define NPTS 16384
#define S 1024
#define KNEI 32
#define MROWS (NB*S*KNEI)   // 262144

typedef float v2f __attribute__((ext_vector_type(2)));

// Value-only max combine via DPP, bound_ctrl=1 (invalid lanes read 0 --
// safe identity: all reduced values are >= 0).
#define DPP_MAXF0(CTRL, v) do {                                               \
    int _o = __builtin_amdgcn_update_dpp(0, __float_as_int(v),                \
                                         (CTRL), 0xF, 0xF, true);             \
    (v) = fmaxf((v), __int_as_float(_o));                                     \
  } while (0)

// u32 int min combine via DPP, identity INT_MAX via the 'old' operand
// (bound_ctrl=false keeps old where the source lane is invalid).
#define DPP_MINI(CTRL, v) do {                                                \
    int _o = __builtin_amdgcn_update_dpp((int)0x7fffffff, (v),                \
                                         (CTRL), 0xF, 0xF, false);            \
    (v) = (_o < (v)) ? _o : (v);                                              \
  } while (0)

// u64 key max combine via DPP halves, bound_ctrl=1 (identity 0 always loses:
// every real key >= 1 because of the 16384-idx field).
#define DPP_MAXK0(CTRL, k) do {                                               \
    int _olo = __builtin_amdgcn_update_dpp(0, (int)(unsigned)(k),             \
                                           (CTRL), 0xF, 0xF, true);           \
    int _ohi = __builtin_amdgcn_update_dpp(0, (int)(unsigned)((k) >> 32),     \
                                           (CTRL), 0xF, 0xF, true);           \
    unsigned long long _ok = (((unsigned long long)(unsigned)_ohi) << 32)     \
                           | (unsigned)_olo;                                  \
    if (_ok > (k)) (k) = _ok;                                                 \
  } while (0)

#define DPP_ROW_SHR1   0x111
#define DPP_ROW_SHR2   0x112
#define DPP_ROW_SHR4   0x114
#define DPP_ROW_SHR8   0x118
#define DPP_ROW_BCAST15 0x142
#define DPP_ROW_BCAST31 0x143

// ---------------------------------------------------------------------------
// FPS r14: r10-r13 established the single-CU loop is VALU-issue-bound at
// ~290-370 instrs/wave/step (~1.5ms floor) and cross-block sync is 14x worse
// (r11). Algorithmic fix -- exact QuickFPS-style skipping:
//   preamble: Morton-bin (4096 cells) the batch's points; scatter sorted
//     coords to global scratch (h2 region, dead during fps); permutation in
//     LDS (u16). Each thread now owns 16 SPATIALLY LOCAL points + their box.
//   per step: lb = clamped distance from centroid to box. If
//     lb2*0.99999f >= ub (cached max of this thread's dists), all 16
//     min-updates provably keep dist unchanged (conservative margin >=1e-5
//     vs <2e-6 accumulated rel fp error) -> skip the 16-point pass.
//   dist[] regs are therefore always current; bv = ub always equals the
//   true max. Locate is exec-guarded to waves holding the wave-max; orig
//   index from LDS perm; key = dist_bits<<15 | (16384-orig_idx) preserves
//   numpy first-occurrence argmax through the permutation.
// Correctness is independent of spatial quality (bad binning = slow, not
// wrong). Distance math unchanged: contract off, ((dx^2+dy^2)+dz^2).
// ---------------------------------------------------------------------------
__global__ __launch_bounds__(1024, 4) void fps_kernel(const float* __restrict__ pos,
                                                      float* __restrict__ centers,
                                                      float* __restrict__ sbuf){
#pragma clang fp contract(off)
  __shared__ int hist[4096];
  __shared__ int ts[1024];
  __shared__ unsigned short perm[16384];
  __shared__ unsigned long long lslot[2][16];
  const int b = blockIdx.x;
  const int t = threadIdx.x;
  const int wid = t >> 6, lane = t & 63;
  const float* pb = pos + (size_t)b * NPTS * 3;
  float* ssx = sbuf + (size_t)b * 3 * NPTS;
  float* ssy = ssx + NPTS;
  float* ssz = ssy + NPTS;
  const int p0 = t * 16;

  // ---- phase 0: load raw points, Morton cell ids ----
  float c[48];
  {
    const float4* src = (const float4*)(pb + (size_t)t*48);
#pragma unroll
    for (int q = 0; q < 12; ++q) *(float4*)&c[q*4] = src[q];
  }
  int cell[16];
#pragma unroll
  for (int j = 0; j < 16; ++j){
    float x = c[3*j], y = c[3*j+1], z = c[3*j+2];
    int ix = (int)(x * 16.f); ix = ix < 0 ? 0 : (ix > 15 ? 15 : ix);
    int iy = (int)(y * 16.f); iy = iy < 0 ? 0 : (iy > 15 ? 15 : iy);
    int iz = (int)(z * 16.f); iz = iz < 0 ? 0 : (iz > 15 ? 15 : iz);
    int m = 0;
#pragma unroll
    for (int k = 0; k < 4; ++k){
      m |= ((ix >> k) & 1) << (3*k + 2);
      m |= ((iy >> k) & 1) << (3*k + 1);
      m |= ((iz >> k) & 1) << (3*k + 0);
    }
    cell[j] = m;
  }
  // histogram
#pragma unroll
  for (int i = 0; i < 4; ++i) hist[t*4 + i] = 0;
  __syncthreads();
#pragma unroll
  for (int j = 0; j < 16; ++j) atomicAdd(&hist[cell[j]], 1);
  __syncthreads();
  // prefix sum: per-thread 4 cells -> Hillis-Steele over 1024 thread sums
  int h0 = hist[t*4], h1 = hist[t*4+1], h2v = hist[t*4+2], h3 = hist[t*4+3];
  (void)h3;
  ts[t] = h0 + h1 + h2v + hist[t*4+3];
  __syncthreads();
  for (int off = 1; off < 1024; off <<= 1){
    int add = (t >= off) ? ts[t - off] : 0;
    __syncthreads();
    ts[t] += add;
    __syncthreads();
  }
  {
    int base = (t == 0) ? 0 : ts[t-1];
    hist[t*4]   = base;
    hist[t*4+1] = base + h0;
    hist[t*4+2] = base + h0 + h1;
    hist[t*4+3] = base + h0 + h1 + h2v;
  }
  __syncthreads();
  // scatter sorted coords to global scratch; permutation to LDS
#pragma unroll
  for (int j = 0; j < 16; ++j){
    int dst = atomicAdd(&hist[cell[j]], 1);
    ssx[dst] = c[3*j];
    ssy[dst] = c[3*j+1];
    ssz[dst] = c[3*j+2];
    perm[dst] = (unsigned short)(p0 + j);
  }
  __syncthreads();

  // ---- reload sorted points into registers; per-thread bounding box ----
  v2f px[8], py[8], pz[8], dist[8];
#pragma unroll
  for (int g = 0; g < 4; ++g){
    float4 vx = *(const float4*)&ssx[p0 + g*4];
    float4 vy = *(const float4*)&ssy[p0 + g*4];
    float4 vz = *(const float4*)&ssz[p0 + g*4];
    px[g*2]   = (v2f){vx.x, vx.y}; px[g*2+1] = (v2f){vx.z, vx.w};
    py[g*2]   = (v2f){vy.x, vy.y}; py[g*2+1] = (v2f){vy.z, vy.w};
    pz[g*2]   = (v2f){vz.x, vz.y}; pz[g*2+1] = (v2f){vz.z, vz.w};
  }
  float bxl = 1e30f, bxh = -1e30f, byl = 1e30f, byh = -1e30f;
  float bzl = 1e30f, bzh = -1e30f;
#pragma unroll
  for (int j = 0; j < 8; ++j){
    asm volatile("" : "+v"(px[j]), "+v"(py[j]), "+v"(pz[j]));  // no remat
    bxl = fminf(bxl, fminf(px[j].x, px[j].y));
    bxh = fmaxf(bxh, fmaxf(px[j].x, px[j].y));
    byl = fminf(byl, fminf(py[j].x, py[j].y));
    byh = fmaxf(byh, fmaxf(py[j].x, py[j].y));
    bzl = fminf(bzl, fminf(pz[j].x, pz[j].y));
    bzh = fmaxf(bzh, fmaxf(pz[j].x, pz[j].y));
    dist[j] = (v2f){1e10f, 1e10f};
  }
  float ub = 1e10f;
  float cx = pb[0], cy = pb[1], cz = pb[2];    // far=0 initial centroid

  // ---- phase 1: the serial FPS loop ----
  for (int s = 0; s < S; ++s){
    if (t == 0){
      float* cd = centers + (size_t)(b*S + s)*3;
      cd[0] = cx; cd[1] = cy; cd[2] = cz;
    }
    // box skip test (conservative margin: provably no dist changes)
    float lx = fmaxf(fmaxf(bxl - cx, cx - bxh), 0.f);
    float ly = fmaxf(fmaxf(byl - cy, cy - byh), 0.f);
    float lz = fmaxf(fmaxf(bzl - cz, cz - bzh), 0.f);
    float lb2 = ((lx*lx + ly*ly) + lz*lz);
    if (!(lb2 * 0.99999f >= ub)){
      v2f cx2 = (v2f){cx, cx}, cy2 = (v2f){cy, cy}, cz2 = (v2f){cz, cz};
      float nb = 0.0f;
#pragma unroll
      for (int j = 0; j < 8; ++j){
        v2f dx = px[j] - cx2;
        v2f dy = py[j] - cy2;
        v2f dz = pz[j] - cz2;
        v2f t1 = dx * dx;
        v2f t2 = dy * dy;
        v2f t3 = dz * dz;
        v2f d  = (t1 + t2) + t3;         // ((dx^2+dy^2)+dz^2)
        v2f od = dist[j];
        v2f nd = (v2f){__builtin_fminf(od.x, d.x), __builtin_fminf(od.y, d.y)};
        dist[j] = nd;
        nb = fmaxf(fmaxf(nb, nd.x), nd.y);   // v_max3
      }
      ub = nb;
    }
    float bv = ub;
    // wave-level value max (DPP)
    DPP_MAXF0(DPP_ROW_SHR1,   bv);
    DPP_MAXF0(DPP_ROW_SHR2,   bv);
    DPP_MAXF0(DPP_ROW_SHR4,   bv);
    DPP_MAXF0(DPP_ROW_SHR8,   bv);
    DPP_MAXF0(DPP_ROW_BCAST15, bv);
    DPP_MAXF0(DPP_ROW_BCAST31, bv);   // lane 63 = wave max
    float bmw = __int_as_float(
        __builtin_amdgcn_readlane(__float_as_int(bv), 63));
    // guarded locate: min ORIGINAL index among this thread's dist==bmw slots
    int mi = 0x7fffffff;
    if (ub == bmw){
#pragma unroll
      for (int j = 0; j < 8; ++j){
        if (dist[j].x == bmw){ int o = (int)perm[p0 + 2*j];     mi = o < mi ? o : mi; }
        if (dist[j].y == bmw){ int o = (int)perm[p0 + 2*j + 1]; mi = o < mi ? o : mi; }
      }
    }
    DPP_MINI(DPP_ROW_SHR1,   mi);
    DPP_MINI(DPP_ROW_SHR2,   mi);
    DPP_MINI(DPP_ROW_SHR4,   mi);
    DPP_MINI(DPP_ROW_SHR8,   mi);
    DPP_MINI(DPP_ROW_BCAST15, mi);
    DPP_MINI(DPP_ROW_BCAST31, mi);
    int miw = __builtin_amdgcn_readlane(mi, 63);
    const int par = s & 1;
    if (lane == 0){
      lslot[par][wid] = ((unsigned long long)__float_as_uint(bmw) << 15)
                      | (unsigned long long)(16384 - miw);
    }
    __syncthreads();
    // cross-wave u64 reduce: 16 slots on lanes 0-15 of each row
    unsigned long long kk = lslot[par][lane & 15];
    DPP_MAXK0(DPP_ROW_SHR1, kk);
    DPP_MAXK0(DPP_ROW_SHR2, kk);
    DPP_MAXK0(DPP_ROW_SHR4, kk);
    DPP_MAXK0(DPP_ROW_SHR8, kk);
    unsigned klo = (unsigned)__builtin_amdgcn_readlane((int)(unsigned)kk, 15);
    unsigned khi = (unsigned)__builtin_amdgcn_readlane((int)(unsigned)(kk >> 32), 15);
    unsigned long long kmax = (((unsigned long long)khi) << 32) | klo;
    int ufi = 16384 - (int)(kmax & 0x7FFFull);
    const float* cp = pb + (size_t)ufi*3;   // uniform -> s_load, L2-hot
    cx = cp[0]; cy = cp[1]; cz = cp[2];
  }
}

// ---------------------------------------------------------------------------
// Ball query: one wave per center. Ordered compaction of the first 32
// in-radius indices (ascending index order == jnp.sort-then-truncate).
// ---------------------------------------------------------------------------
__global__ __launch_bounds__(256) void ballq_kernel(const float* __restrict__ pos,
                                                    const float* __restrict__ centers,
                                                    int* __restrict__ idx){
#pragma clang fp contract(off)
  const float R2 = (float)(0.2*0.2);   // match Python double 0.2*0.2 -> f32
  int wid  = blockIdx.x*4 + (threadIdx.x >> 6);
  int lane = threadIdx.x & 63;
  int b = wid >> 10;                   // wid / S
  const float* pb = pos + (size_t)b * NPTS * 3;
  float cx = centers[wid*3+0], cy = centers[wid*3+1], cz = centers[wid*3+2];
  int* out = idx + wid*KNEI;
  int count = 0; int first = -1;
  for (int base = 0; base < NPTS; base += 64){
    int p = base + lane;
    float dx = pb[p*3+0]-cx, dy = pb[p*3+1]-cy, dz = pb[p*3+2]-cz;
    float t1 = dx*dx, t2 = dy*dy, t3 = dz*dz;
    float d = (t1 + t2) + t3;
    bool inr = d <= R2;
    unsigned long long mask = __ballot(inr);
    if (count == 0 && mask) first = base + __builtin_ctzll(mask);
    if (inr){
      int slot = count + __popcll(mask & ((1ull << lane) - 1ull));
      if (slot < KNEI) out[slot] = p;
    }
    count += __popcll(mask);
    if (count >= KNEI) break;
  }
  if (count < KNEI){
    for (int slot = count + lane; slot < KNEI; slot += 64) out[slot] = first;
  }
}

// ---------------------------------------------------------------------------
// GEMM1 sem: h1[m][0:64] = feat[b, idx[m], :] @ w(64x64) + bias.
// Block: 256 threads, 64-row tile. Also accumulates per-channel sum/sumsq.
// ---------------------------------------------------------------------------
__global__ __launch_bounds__(256) void gemm_sem1(const float* __restrict__ feat,
    const int* __restrict__ idx, const float* __restrict__ w,
    const float* __restrict__ bias, float* __restrict__ h1,
    float* __restrict__ stat){
  __shared__ float xs[64][68];
  __shared__ float wsh[64][64];
  const int tid = threadIdx.x;
  const int m0 = blockIdx.x * 64;
#pragma unroll
  for (int i = 0; i < 4; ++i){
    int q = tid + i*256;                 // 1024 quads of w (64x64)
    int r = q >> 4, c4 = q & 15;
    *(float4*)&wsh[r][c4*4] = *(const float4*)&w[r*64 + c4*4];
  }
#pragma unroll
  for (int i = 0; i < 4; ++i){
    int q = tid + i*256;                 // 1024 quads of x tile (64x64)
    int r = q >> 4, c4 = q & 15;
    int m = m0 + r;
    int nb = idx[m];
    int b = m >> 15;                     // m / (S*KNEI)
    const float* fr = feat + ((size_t)b*NPTS + nb)*64;
    *(float4*)&xs[r][c4*4] = *(const float4*)&fr[c4*4];
  }
  __syncthreads();
  const int g  = tid & 7;                // channel group: 8 channels
  const int rt = tid >> 3;               // 32 row-threads, 2 rows each
  const int r0 = rt * 2;
  float acc[2][8];
#pragma unroll
  for (int c = 0; c < 8; ++c){ float bb = bias[g*8+c]; acc[0][c] = bb; acc[1][c] = bb; }
  for (int k = 0; k < 64; ++k){
    float x0 = xs[r0][k], x1 = xs[r0+1][k];
    float4 wa = *(float4*)&wsh[k][g*8];
    float4 wb = *(float4*)&wsh[k][g*8+4];
    float wv[8] = {wa.x,wa.y,wa.z,wa.w,wb.x,wb.y,wb.z,wb.w};
#pragma unroll
    for (int c = 0; c < 8; ++c){ acc[0][c] += x0*wv[c]; acc[1][c] += x1*wv[c]; }
  }
#pragma unroll
  for (int r = 0; r < 2; ++r){
    float* dst = h1 + (size_t)(m0 + r0 + r)*64 + g*8;
    *(float4*)dst     = make_float4(acc[r][0],acc[r][1],acc[r][2],acc[r][3]);
    *(float4*)(dst+4) = make_float4(acc[r][4],acc[r][5],acc[r][6],acc[r][7]);
  }
  float ls[8], lq[8];
#pragma unroll
  for (int c = 0; c < 8; ++c){
    ls[c] = acc[0][c] + acc[1][c];
    lq[c] = acc[0][c]*acc[0][c] + acc[1][c]*acc[1][c];
  }
  __syncthreads();
  float* red  = &xs[0][0];
  float* redq = &wsh[0][0];
#pragma unroll
  for (int c = 0; c < 8; ++c){
    red[(g*8+c)*32 + rt]  = ls[c];
    redq[(g*8+c)*32 + rt] = lq[c];
  }
  __syncthreads();
  if (tid < 128){
    int c = tid & 63;
    const float* src = (tid < 64) ? red : redq;
    float a2 = 0.f;
    for (int i = 0; i < 32; ++i) a2 += src[c*32+i];
    atomicAdd(&stat[(tid < 64 ? 0 : 64) + c], a2);
  }
}

// ---------------------------------------------------------------------------
// GEMM2 (sem & geo layer 2): x = relu(a*hin+d) (folded BN1), out 128 ch.
// ---------------------------------------------------------------------------
__global__ __launch_bounds__(256) void gemm2_kernel(const float* __restrict__ hin,
    const float* __restrict__ abn, const float* __restrict__ dbn,
    const float* __restrict__ w, const float* __restrict__ bias,
    float* __restrict__ hout, float* __restrict__ stat){
  __shared__ float xs[64][68];
  __shared__ float wsh[64][128];
  const int tid = threadIdx.x;
  const int m0 = blockIdx.x * 64;
#pragma unroll
  for (int i = 0; i < 8; ++i){
    int q = tid + i*256;                 // 2048 quads of w (64x128)
    int r = q >> 5, c4 = q & 31;
    *(float4*)&wsh[r][c4*4] = *(const float4*)&w[r*128 + c4*4];
  }
#pragma unroll
  for (int i = 0; i < 4; ++i){
    int q = tid + i*256;
    int r = q >> 4, c4 = q & 15;
    float4 v  = *(const float4*)&hin[(size_t)(m0+r)*64 + c4*4];
    float4 av = *(const float4*)&abn[c4*4];
    float4 dv = *(const float4*)&dbn[c4*4];
    v.x = fmaxf(v.x*av.x + dv.x, 0.f);
    v.y = fmaxf(v.y*av.y + dv.y, 0.f);
    v.z = fmaxf(v.z*av.z + dv.z, 0.f);
    v.w = fmaxf(v.w*av.w + dv.w, 0.f);
    *(float4*)&xs[r][c4*4] = v;
  }
  __syncthreads();
  const int g  = tid & 15;               // 16 groups x 8 ch = 128
  const int rt = tid >> 4;               // 16 row-threads x 4 rows = 64
  const int r0 = rt * 4;
  float acc[4][8];
#pragma unroll
  for (int c = 0; c < 8; ++c){
    float bb = bias[g*8+c];
    acc[0][c]=bb; acc[1][c]=bb; acc[2][c]=bb; acc[3][c]=bb;
  }
  for (int k = 0; k < 64; ++k){
    float x0 = xs[r0][k], x1 = xs[r0+1][k], x2 = xs[r0+2][k], x3 = xs[r0+3][k];
    float4 wa = *(float4*)&wsh[k][g*8];
    float4 wb = *(float4*)&wsh[k][g*8+4];
    float wv[8] = {wa.x,wa.y,wa.z,wa.w,wb.x,wb.y,wb.z,wb.w};
#pragma unroll
    for (int c = 0; c < 8; ++c){
      acc[0][c] += x0*wv[c]; acc[1][c] += x1*wv[c];
      acc[2][c] += x2*wv[c]; acc[3][c] += x3*wv[c];
    }
  }
#pragma unroll
  for (int r = 0; r < 4; ++r){
    float* dst = hout + (size_t)(m0 + r0 + r)*128 + g*8;
    *(float4*)dst     = make_float4(acc[r][0],acc[r][1],acc[r][2],acc[r][3]);
    *(float4*)(dst+4) = make_float4(acc[r][4],acc[r][5],acc[r][6],acc[r][7]);
  }
  float ls[8], lq[8];
#pragma unroll
  for (int c = 0; c < 8; ++c){
    ls[c] = acc[0][c]+acc[1][c]+acc[2][c]+acc[3][c];
    lq[c] = acc[0][c]*acc[0][c]+acc[1][c]*acc[1][c]+acc[2][c]*acc[2][c]+acc[3][c]*acc[3][c];
  }
  __syncthreads();
  float* red = &xs[0][0];                // 2048 sums + 2048 sumsq (fits 64*68)
#pragma unroll
  for (int c = 0; c < 8; ++c){
    red[(g*8+c)*16 + rt]        = ls[c];
    red[2048 + (g*8+c)*16 + rt] = lq[c];
  }
  __syncthreads();
  {
    int c = tid & 127;
    int isq = tid >> 7;
    float a2 = 0.f;
    for (int i = 0; i < 16; ++i) a2 += red[isq*2048 + c*16 + i];
    atomicAdd(&stat[isq*128 + c], a2);
  }
}

// ---------------------------------------------------------------------------
// GEMM1 geo: x = [center(3) | grouped_pos(3)] (6 ch) @ w(6x64) + bias.
// ---------------------------------------------------------------------------
__global__ __launch_bounds__(256) void gemm_geo1(const float* __restrict__ pos,
    const float* __restrict__ centers, const int* __restrict__ idx,
    const float* __restrict__ w, const float* __restrict__ bias,
    float* __restrict__ hout, float* __restrict__ stat){
  __shared__ float xs[64][8];
  __shared__ float wsh[6][64];
  __shared__ float red[2048];
  __shared__ float redq[2048];
  const int tid = threadIdx.x;
  const int m0 = blockIdx.x * 64;
  for (int i = tid; i < 384; i += 256) wsh[i >> 6][i & 63] = w[i];
  if (tid < 64){
    int m = m0 + tid;
    int grp = m >> 5;                    // m / KNEI
    int b = m >> 15;
    int nb = idx[m];
    const float* cp = centers + (size_t)grp*3;
    const float* pp = pos + ((size_t)b*NPTS + nb)*3;
    xs[tid][0]=cp[0]; xs[tid][1]=cp[1]; xs[tid][2]=cp[2];
    xs[tid][3]=pp[0]; xs[tid][4]=pp[1]; xs[tid][5]=pp[2];
  }
  __syncthreads();
  const int g  = tid & 7;
  const int rt = tid >> 3;
  const int r0 = rt * 2;
  float acc[2][8];
#pragma unroll
  for (int c = 0; c < 8; ++c){ float bb = bias[g*8+c]; acc[0][c]=bb; acc[1][c]=bb; }
#pragma unroll
  for (int k = 0; k < 6; ++k){
    float x0 = xs[r0][k], x1 = xs[r0+1][k];
    float4 wa = *(float4*)&wsh[k][g*8];
    float4 wb = *(float4*)&wsh[k][g*8+4];
    float wv[8] = {wa.x,wa.y,wa.z,wa.w,wb.x,wb.y,wb.z,wb.w};
#pragma unroll
    for (int c = 0; c < 8; ++c){ acc[0][c] += x0*wv[c]; acc[1][c] += x1*wv[c]; }
  }
#pragma unroll
  for (int r = 0; r < 2; ++r){
    float* dst = hout + (size_t)(m0 + r0 + r)*64 + g*8;
    *(float4*)dst     = make_float4(acc[r][0],acc[r][1],acc[r][2],acc[r][3]);
    *(float4*)(dst+4) = make_float4(acc[r][4],acc[r][5],acc[r][6],acc[r][7]);
  }
  float ls[8], lq[8];
#pragma unroll
  for (int c = 0; c < 8; ++c){
    ls[c] = acc[0][c] + acc[1][c];
    lq[c] = acc[0][c]*acc[0][c] + acc[1][c]*acc[1][c];
  }
#pragma unroll
  for (int c = 0; c < 8; ++c){
    red[(g*8+c)*32 + rt]  = ls[c];
    redq[(g*8+c)*32 + rt] = lq[c];
  }
  __syncthreads();
  if (tid < 128){
    int c = tid & 63;
    const float* src = (tid < 64) ? red : redq;
    float a2 = 0.f;
    for (int i = 0; i < 32; ++i) a2 += src[c*32+i];
    atomicAdd(&stat[(tid < 64 ? 0 : 64) + c], a2);
  }
}

// ---------------------------------------------------------------------------
// BN finalize: fold stats into per-channel scale/shift a,d.
// ---------------------------------------------------------------------------
__global__ void bn_finalize(const float* __restrict__ stat,
                            const float* __restrict__ gam, const float* __restrict__ bet,
                            float* __restrict__ a, float* __restrict__ d, int C){
  int c = threadIdx.x;
  if (c >= C) return;
  const float invM = 1.0f / (float)MROWS;
  float mu  = stat[c] * invM;
  float ex2 = stat[C + c] * invM;
  float var = ex2 - mu*mu;
  float aa = gam[c] * rsqrtf(var + 1e-5f);
  a[c] = aa;
  d[c] = bet[c] - mu*aa;
}

// ---------------------------------------------------------------------------
// Max over K with folded BN2 + ReLU: out[grp][c] = relu(max_k (a*h+d)).
// ---------------------------------------------------------------------------
__global__ __launch_bounds__(256) void maxpool_kernel(const float* __restrict__ hin,
    const float* __restrict__ abn, const float* __restrict__ dbn,
    float* __restrict__ out){
  const int tid = threadIdx.x;
  const int grp = blockIdx.x*8 + (tid >> 5);
  const int c4 = tid & 31;
  const float* base = hin + (size_t)grp*KNEI*128 + c4*4;
  float4 a = *(const float4*)&abn[c4*4];
  float4 d = *(const float4*)&dbn[c4*4];
  float4 m = make_float4(-3.4e38f,-3.4e38f,-3.4e38f,-3.4e38f);
  for (int k = 0; k < KNEI; ++k){
    float4 v = *(const float4*)&base[(size_t)k*128];
    m.x = fmaxf(m.x, v.x*a.x + d.x);
    m.y = fmaxf(m.y, v.y*a.y + d.y);
    m.z = fmaxf(m.z, v.z*a.z + d.z);
    m.w = fmaxf(m.w, v.w*a.w + d.w);
  }
  m.x = fmaxf(m.x, 0.f); m.y = fmaxf(m.y, 0.f);
  m.z = fmaxf(m.z, 0.f); m.w = fmaxf(m.w, 0.f);
  *(float4*)&out[(size_t)grp*128 + c4*4] = m;
}

__global__ void zero_kernel(float* __restrict__ p, int n){
  int i = blockIdx.x*blockDim.x + threadIdx.x;
  if (i < n) p[i] = 0.f;
}

extern "C" void kernel_launch(void* const* d_in, const int* in_sizes, int n_in,
                              void* d_out, int out_size, void* d_ws, size_t ws_size,
                              hipStream_t stream){
  const float* pos   = (const float*)d_in[0];
  const float* feat  = (const float*)d_in[1];
  const float* w_s1  = (const float*)d_in[2];
  const float* b_s1  = (const float*)d_in[3];
  const float* g_s1  = (const float*)d_in[4];
  const float* be_s1 = (const float*)d_in[5];
  const float* w_s2  = (const float*)d_in[6];
  const float* b_s2  = (const float*)d_in[7];
  const float* g_s2  = (const float*)d_in[8];
  const float* be_s2 = (const float*)d_in[9];
  const float* w_g1  = (const float*)d_in[10];
  const float* b_g1  = (const float*)d_in[11];
  const float* g_g1  = (const float*)d_in[12];
  const float* be_g1 = (const float*)d_in[13];
  const float* w_g2  = (const float*)d_in[14];
  const float* b_g2  = (const float*)d_in[15];
  const float* g_g2  = (const float*)d_in[16];
  const float* be_g2 = (const float*)d_in[17];
  float* outp = (float*)d_out;
  float* wsf  = (float*)d_ws;

  // workspace layout (floats):
  float* centers = wsf;                         // 8192*3 = 24576
  int*   idxp    = (int*)(wsf + 24576);         // 262144
  float* stats   = wsf + 24576 + 262144;        // 768
  float* bnad    = stats + 768;                 // 768
  float* h1      = wsf + 288256;                // 262144*64
  float* h2      = h1 + (size_t)MROWS*64;       // 262144*128
  // total = 50,619,904 floats = ~193.1 MiB
  // fps sorted-coords scratch lives at the head of h2 (8*3*16384 floats =
  // 1.5 MB) -- h2 is dead until gemm2, launched after fps completes.
  float* sortbuf = h2;

  float* st1 = stats;        // 64 sum + 64 sq
  float* st2 = stats + 128;  // 128 + 128
  float* st3 = stats + 384;  // 64 + 64
  float* st4 = stats + 512;  // 128 + 128
  float* a1 = bnad;        float* d1 = bnad + 64;
  float* a2 = bnad + 128;  float* d2 = bnad + 256;
  float* a3 = bnad + 384;  float* d3 = bnad + 448;
  float* a4 = bnad + 512;  float* d4 = bnad + 640;

  zero_kernel<<<3, 256, 0, stream>>>(stats, 768);
  fps_kernel<<<NB, 1024, 0, stream>>>(pos, centers, sortbuf);
  ballq_kernel<<<(NB*S)/4, 256, 0, stream>>>(pos, centers, idxp);

  // sem branch
  gemm_sem1<<<MROWS/64, 256, 0, stream>>>(feat, idxp, w_s1, b_s1, h1, st1);
  bn_finalize<<<1, 128, 0, stream>>>(st1, g_s1, be_s1, a1, d1, 64);
  gemm2_kernel<<<MROWS/64, 256, 0, stream>>>(h1, a1, d1, w_s2, b_s2, h2, st2);
  bn_finalize<<<1, 128, 0, stream>>>(st2, g_s2, be_s2, a2, d2, 128);
  maxpool_kernel<<<(NB*S)/8, 256, 0, stream>>>(h2, a2, d2, outp);

  // geo branch (reuses h1/h2)
  gemm_geo1<<<MROWS/64, 256, 0, stream>>>(pos, centers, idxp, w_g1, b_g1, h1, st3);
  bn_finalize<<<1, 128, 0, stream>>>(st3, g_g1, be_g1, a3, d3, 64);
  gemm2_kernel<<<MROWS/64, 256, 0, stream>>>(h1, a3, d3, w_g2, b_g2, h2, st4);
  bn_finalize<<<1, 128, 0, stream>>>(st4, g_g2, be_g2, a4, d4, 128);
  maxpool_kernel<<<(NB*S)/8, 256, 0, stream>>>(h2, a4, d4, outp + (size_t)NB*S*128);
}